// Round 3
// baseline (410.977 us; speedup 1.0000x reference)
//
#include <hip/hip_runtime.h>
#include <hip/hip_bf16.h>

// Problem constants
#define CH   192
#define PIX  4096   // 64*64 per image
#define BSZ  8

using f32x4  = __attribute__((ext_vector_type(4))) float;
using short8 = __attribute__((ext_vector_type(8))) short;

__device__ __forceinline__ float bf2f(unsigned short u) {
    union { unsigned u32; float f; } x; x.u32 = ((unsigned)u) << 16; return x.f;
}
__device__ __forceinline__ unsigned short f2bf(float f) {
    union { float f; unsigned u; } x; x.f = f;
    unsigned u = x.u;
    unsigned r = (u + 0x7FFFu + ((u >> 16) & 1u)) >> 16;  // RNE
    return (unsigned short)r;
}

// ---- prep: fp32 input -> bf16 -------------------------------------------
__global__ void k_cvt_in(const float* __restrict__ in, unsigned short* __restrict__ out) {
    int i = blockIdx.x * 256 + threadIdx.x;       // one float4 per thread
    float4 v = ((const float4*)in)[i];
    ushort4 o;
    o.x = f2bf(v.x); o.y = f2bf(v.y); o.z = f2bf(v.z); o.w = f2bf(v.w);
    ((ushort4*)out)[i] = o;
}

// ---- prep: weights -> bf16 (+ws1 tap-major transpose), zero gsum --------
__global__ void k_prep_w(const float* __restrict__ w0, const float* __restrict__ w1,
                         const float* __restrict__ ws0, const float* __restrict__ wo,
                         const float* __restrict__ ws1,
                         unsigned short* __restrict__ w0b, unsigned short* __restrict__ w1b,
                         unsigned short* __restrict__ ws0xb, unsigned short* __restrict__ wob,
                         unsigned short* __restrict__ ws1tb, float* __restrict__ gsum) {
    int i = blockIdx.x * 256 + threadIdx.x;
    if (i < 36864) { w0b[i] = f2bf(w0[i]); return; }
    i -= 36864;
    if (i < 36864) { w1b[i] = f2bf(w1[i]); return; }
    i -= 36864;
    if (i < 36864) { int o = i / 192, k = i % 192; ws0xb[i] = f2bf(ws0[o*384 + k]); return; }
    i -= 36864;
    if (i < 36864) { wob[i] = f2bf(wo[i]); return; }
    i -= 36864;
    if (i < 331776) {  // dest [tap][o][c] <- ws1[(o*192+c)*9 + tap]
        int tap = i / 36864, r = i % 36864, o = r / 192, c = r % 192;
        ws1tb[i] = f2bf(ws1[(o*192 + c)*9 + tap]); return;
    }
    i -= 331776;
    if (i < 1536) gsum[i] = 0.f;
}

// ---- prep: t[b][m][o] = sum_c ws0[o][192+c] * center[b][m][c] -----------
__global__ void k_tcent(const float* __restrict__ ws0, const float* __restrict__ lc,
                        float* __restrict__ tc) {
    int m = blockIdx.x, b = blockIdx.y, o = threadIdx.x;
    __shared__ float cbuf[192];
    cbuf[o] = lc[(b*16 + m)*192 + o];
    __syncthreads();
    float a = 0.f;
    const float* wr = ws0 + o*384 + 192;
    for (int c = 0; c < 192; ++c) a += wr[c] * cbuf[c];
    tc[(b*16 + m)*192 + o] = a;
}

// ---- GEMM: out[b][o][px] = A[o][:] . B[b][:][px] (+epilogue) ------------
// MODE 0: +bias, lrelu, bf16 out            (W0 @ input)
// MODE 1: +bias, bf16 out                   (W1 @ h)
// MODE 2: +bias +center[mask], lrelu, bf16  (Ws0_x @ x)
// MODE 3: B scaled by gvec[k]; +bias +resid, fp32 out (Wo @ (g*out_pre))
template<int MODE>
__global__ __launch_bounds__(256) void k_gemm(
    const unsigned short* __restrict__ A,   // [192][192] bf16
    const unsigned short* __restrict__ B,   // [BSZ][192][PIX] bf16
    const float* __restrict__ bias,         // [192]
    unsigned short* __restrict__ Obf,
    float* __restrict__ Ofp,
    const float* __restrict__ tc,           // [BSZ][16][192]
    const int* __restrict__ mask,           // [BSZ][PIX]
    const float* __restrict__ gvec,         // [BSZ][192]
    const float* __restrict__ resid)        // fp32 [BSZ][192][PIX]
{
    const int b  = blockIdx.y;
    const int n0 = blockIdx.x * 64;
    __shared__ unsigned short Asm[192*32];
    __shared__ unsigned short Bsm[32*64];
    const int tid = threadIdx.x;
    const int lane = tid & 63, wv = tid >> 6;
    f32x4 acc[12];
    #pragma unroll
    for (int m = 0; m < 12; ++m) acc[m] = {0.f, 0.f, 0.f, 0.f};

    const unsigned short* Bb = B + (size_t)b * 192 * PIX;
    const int kB = tid >> 3, p8 = (tid & 7) * 8;

    for (int kc = 0; kc < 192; kc += 32) {
        if (tid < 192) {
            const uint4* s4 = (const uint4*)(A + tid*192 + kc);
            uint4* d4 = (uint4*)(Asm + tid*32);
            d4[0] = s4[0]; d4[1] = s4[1]; d4[2] = s4[2]; d4[3] = s4[3];
        }
        {
            const unsigned short* src = Bb + (size_t)(kc + kB) * PIX + n0 + p8;
            uint4 v = *(const uint4*)src;
            if (MODE == 3) {
                float gs = gvec[b*192 + kc + kB];
                unsigned short* pv = (unsigned short*)&v;
                #pragma unroll
                for (int e = 0; e < 8; ++e) pv[e] = f2bf(bf2f(pv[e]) * gs);
            }
            *(uint4*)(Bsm + kB*64 + p8) = v;
        }
        __syncthreads();
        const int pxl = wv*16 + (lane & 15);
        const int kb0 = (lane >> 4) * 8;
        short8 fb;
        #pragma unroll
        for (int e = 0; e < 8; ++e) fb[e] = (short)Bsm[(kb0 + e)*64 + pxl];
        #pragma unroll
        for (int m = 0; m < 12; ++m) {
            short8 fa = *(const short8*)(Asm + (m*16 + (lane & 15))*32 + kb0);
            acc[m] = __builtin_amdgcn_mfma_f32_16x16x32_bf16(fa, fb, acc[m], 0, 0, 0);
        }
        __syncthreads();
    }

    const int px = n0 + wv*16 + (lane & 15);
    int mi = 0;
    if (MODE == 2) mi = mask[b*PIX + px];
    #pragma unroll
    for (int m = 0; m < 12; ++m) {
        #pragma unroll
        for (int r = 0; r < 4; ++r) {
            int o = m*16 + (lane >> 4)*4 + r;
            float v = acc[m][r] + bias[o];
            if (MODE == 2) v += tc[(b*16 + mi)*192 + o];
            if (MODE == 0 || MODE == 2) v = v > 0.f ? v : 0.1f * v;
            size_t oidx = ((size_t)b*192 + o)*PIX + px;
            if (MODE == 3) Ofp[oidx] = v + resid[oidx];
            else           Obf[oidx] = f2bf(v);
        }
    }
}

// ---- 3x3 conv as 9 shifted GEMM accumulations; one image row per block --
__global__ __launch_bounds__(256) void k_conv3(
    const unsigned short* __restrict__ Wt,  // [9][192][192] bf16, tap-major
    const unsigned short* __restrict__ Y0,  // [BSZ][192][PIX] bf16
    const float* __restrict__ bias,
    unsigned short* __restrict__ Y1)
{
    const int b = blockIdx.y;
    const int h = blockIdx.x;
    __shared__ unsigned short Asm[192*32];
    __shared__ unsigned short Bsm[32*64];
    const int tid = threadIdx.x, lane = tid & 63, wv = tid >> 6;
    f32x4 acc[12];
    #pragma unroll
    for (int m = 0; m < 12; ++m) acc[m] = {0.f, 0.f, 0.f, 0.f};
    const int kB = tid >> 3, p8 = (tid & 7) * 8;

    for (int tap = 0; tap < 9; ++tap) {
        const int dr = tap/3 - 1, dc = tap%3 - 1;
        const int hh = h + dr;
        if (hh < 0 || hh >= 64) continue;   // zero-pad rows: uniform skip
        const unsigned short* At = Wt + tap * 36864;
        for (int kc = 0; kc < 192; kc += 32) {
            if (tid < 192) {
                const uint4* s4 = (const uint4*)(At + tid*192 + kc);
                uint4* d4 = (uint4*)(Asm + tid*32);
                d4[0] = s4[0]; d4[1] = s4[1]; d4[2] = s4[2]; d4[3] = s4[3];
            }
            {
                const unsigned short* src = Y0 + ((size_t)b*192 + kc + kB)*PIX + hh*64;
                #pragma unroll
                for (int e = 0; e < 8; ++e) {
                    int w = p8 + e + dc;
                    Bsm[kB*64 + p8 + e] = (w >= 0 && w < 64) ? src[w] : (unsigned short)0;
                }
            }
            __syncthreads();
            const int pxl = wv*16 + (lane & 15);
            const int kb0 = (lane >> 4) * 8;
            short8 fb;
            #pragma unroll
            for (int e = 0; e < 8; ++e) fb[e] = (short)Bsm[(kb0 + e)*64 + pxl];
            #pragma unroll
            for (int m = 0; m < 12; ++m) {
                short8 fa = *(const short8*)(Asm + (m*16 + (lane & 15))*32 + kb0);
                acc[m] = __builtin_amdgcn_mfma_f32_16x16x32_bf16(fa, fb, acc[m], 0, 0, 0);
            }
            __syncthreads();
        }
    }

    const int px = h*64 + wv*16 + (lane & 15);
    #pragma unroll
    for (int m = 0; m < 12; ++m) {
        #pragma unroll
        for (int r = 0; r < 4; ++r) {
            int o = m*16 + (lane >> 4)*4 + r;
            float v = acc[m][r] + bias[o];
            v = v > 0.f ? v : 0.1f * v;
            Y1[((size_t)b*192 + o)*PIX + px] = f2bf(v);
        }
    }
}

// ---- fused depthwise-3x3 (k_sp gen) + dynamic conv + gate-mean reduce ---
__global__ __launch_bounds__(256) void k_dwdyn(
    const unsigned short* __restrict__ Y1,
    const unsigned short* __restrict__ X,
    const float* __restrict__ ws2,          // [1728][9]
    const float* __restrict__ bs2,          // [1728]
    unsigned short* __restrict__ OP,
    float* __restrict__ gsum)               // [BSZ][192]
{
    const int b = blockIdx.z, c = blockIdx.y, hb = blockIdx.x;
    const int h0 = hb * 4;
    __shared__ float wsm[9][9];             // [j][tap]
    __shared__ float bsm[9];
    __shared__ unsigned short ysm[6][66];
    __shared__ unsigned short xsm[6][66];
    __shared__ float red[4];
    const int tid = threadIdx.x;
    if (tid < 81) wsm[tid/9][tid%9] = ws2[(c*9 + tid/9)*9 + tid%9];
    if (tid >= 81 && tid < 90) bsm[tid-81] = bs2[c*9 + tid - 81];
    const size_t cb = ((size_t)b*192 + c) * PIX;
    for (int i = tid; i < 396; i += 256) {
        int r = i / 66, cc = i % 66;
        int hh = h0 + r - 1, ww = cc - 1;
        bool ok = (hh >= 0 && hh < 64 && ww >= 0 && ww < 64);
        size_t idx = cb + (size_t)(hh*64 + ww);
        ysm[r][cc] = ok ? Y1[idx] : (unsigned short)0;
        xsm[r][cc] = ok ? X[idx]  : (unsigned short)0;
    }
    __syncthreads();
    const int r = tid >> 6, w = tid & 63;
    float ksp[9];
    #pragma unroll
    for (int j = 0; j < 9; ++j) ksp[j] = bsm[j];
    #pragma unroll
    for (int tap = 0; tap < 9; ++tap) {
        float yv = bf2f(ysm[r + tap/3][w + tap%3]);
        #pragma unroll
        for (int j = 0; j < 9; ++j) ksp[j] += yv * wsm[j][tap];
    }
    float out = 0.f;
    #pragma unroll
    for (int tap = 0; tap < 9; ++tap)
        out += bf2f(xsm[r + tap/3][w + tap%3]) * ksp[tap];
    OP[cb + (size_t)((h0 + r)*64 + w)] = f2bf(out);
    float s = out;
    #pragma unroll
    for (int off = 32; off > 0; off >>= 1) s += __shfl_down(s, off);
    if ((tid & 63) == 0) red[tid >> 6] = s;
    __syncthreads();
    if (tid == 0) atomicAdd(&gsum[b*192 + c], red[0] + red[1] + red[2] + red[3]);
}

// ---- SE gate: g = sigmoid(Wc1 @ lrelu(Wc0 @ mean + bc0) + bc1) ----------
__global__ void k_gate(const float* __restrict__ gsum,
                       const float* __restrict__ wc0, const float* __restrict__ bc0,
                       const float* __restrict__ wc1, const float* __restrict__ bc1,
                       float* __restrict__ gvec)
{
    const int b = blockIdx.x, t = threadIdx.x;
    __shared__ float mean[192], s1[192];
    mean[t] = gsum[b*192 + t] * (1.f/4096.f);
    __syncthreads();
    float a = bc0[t];
    const float* w = wc0 + t*192;
    for (int i = 0; i < 192; ++i) a += w[i] * mean[i];
    s1[t] = a > 0.f ? a : 0.1f * a;
    __syncthreads();
    float a2 = bc1[t];
    const float* w2 = wc1 + t*192;
    for (int i = 0; i < 192; ++i) a2 += w2[i] * s1[i];
    gvec[b*192 + t] = 1.f / (1.f + __expf(-a2));
}

extern "C" void kernel_launch(void* const* d_in, const int* in_sizes, int n_in,
                              void* d_out, int out_size, void* d_ws, size_t ws_size,
                              hipStream_t stream)
{
    const float* input = (const float*)d_in[0];
    const float* lc    = (const float*)d_in[1];
    const int*   mask  = (const int*)d_in[2];
    const float* w0  = (const float*)d_in[3];
    const float* b0  = (const float*)d_in[4];
    const float* w1  = (const float*)d_in[5];
    const float* b1  = (const float*)d_in[6];
    const float* ws0 = (const float*)d_in[7];
    const float* bs0 = (const float*)d_in[8];
    const float* ws1 = (const float*)d_in[9];
    const float* bs1 = (const float*)d_in[10];
    const float* ws2 = (const float*)d_in[11];
    const float* bs2 = (const float*)d_in[12];
    const float* wc0 = (const float*)d_in[13];
    const float* bc0 = (const float*)d_in[14];
    const float* wc1 = (const float*)d_in[15];
    const float* bc1 = (const float*)d_in[16];
    const float* wo  = (const float*)d_in[17];
    const float* bo  = (const float*)d_in[18];

    char* ws = (char*)d_ws;
    size_t off = 0;
    auto alloc = [&](size_t bytes) {
        void* p = ws + off; off = (off + bytes + 255) & ~(size_t)255; return p;
    };
    const size_t act_b = (size_t)BSZ * CH * PIX * 2;
    unsigned short* in_bf = (unsigned short*)alloc(act_b);
    unsigned short* h_bf  = (unsigned short*)alloc(act_b);
    unsigned short* x_bf  = (unsigned short*)alloc(act_b);
    unsigned short* y0_bf = (unsigned short*)alloc(act_b);
    unsigned short* y1_bf = (unsigned short*)alloc(act_b);
    unsigned short* op_bf = (unsigned short*)alloc(act_b);
    unsigned short* w0b   = (unsigned short*)alloc(36864*2);
    unsigned short* w1b   = (unsigned short*)alloc(36864*2);
    unsigned short* ws0xb = (unsigned short*)alloc(36864*2);
    unsigned short* wob   = (unsigned short*)alloc(36864*2);
    unsigned short* ws1tb = (unsigned short*)alloc(331776*2);
    float* tc   = (float*)alloc(8*16*192*4);
    float* gsum = (float*)alloc(1536*4);
    float* gvec = (float*)alloc(1536*4);

    k_cvt_in<<<6144, 256, 0, stream>>>(input, in_bf);
    k_prep_w<<<1878, 256, 0, stream>>>(w0, w1, ws0, wo, ws1, w0b, w1b, ws0xb, wob, ws1tb, gsum);
    k_tcent<<<dim3(16, 8), 192, 0, stream>>>(ws0, lc, tc);

    dim3 gg(64, 8);
    k_gemm<0><<<gg, 256, 0, stream>>>(w0b,   in_bf, b0,  h_bf,  nullptr, nullptr, nullptr, nullptr, nullptr);
    k_gemm<1><<<gg, 256, 0, stream>>>(w1b,   h_bf,  b1,  x_bf,  nullptr, nullptr, nullptr, nullptr, nullptr);
    k_gemm<2><<<gg, 256, 0, stream>>>(ws0xb, x_bf,  bs0, y0_bf, nullptr, tc,      mask,    nullptr, nullptr);
    k_conv3<<<gg, 256, 0, stream>>>(ws1tb, y0_bf, bs1, y1_bf);
    k_dwdyn<<<dim3(16, 192, 8), 256, 0, stream>>>(y1_bf, x_bf, ws2, bs2, op_bf, gsum);
    k_gate<<<8, 192, 0, stream>>>(gsum, wc0, bc0, wc1, bc1, gvec);
    k_gemm<3><<<gg, 256, 0, stream>>>(wob, op_bf, bo, nullptr, (float*)d_out, nullptr, nullptr, gvec, input);
}

// Round 4
// 246.867 us; speedup vs baseline: 1.6648x; 1.6648x over previous
//
#include <hip/hip_runtime.h>
#include <hip/hip_bf16.h>

#define CH   192
#define PIX  4096   // 64*64 per image
#define BSZ  8

using f32x4  = __attribute__((ext_vector_type(4))) float;
using short8 = __attribute__((ext_vector_type(8))) short;

__device__ __forceinline__ float bf2f(unsigned short u) {
    union { unsigned u32; float f; } x; x.u32 = ((unsigned)u) << 16; return x.f;
}
__device__ __forceinline__ unsigned short f2bf(float f) {
    union { float f; unsigned u; } x; x.f = f;
    unsigned u = x.u;
    unsigned r = (u + 0x7FFFu + ((u >> 16) & 1u)) >> 16;  // RNE
    return (unsigned short)r;
}

// B-fragment gather: 8 ushorts at rows k0..k0+7 (stride 66), col px.
// stride 66 => bank = (k + px/2 + 8*(k/8)) pattern covers all 32 banks: conflict-free.
__device__ __forceinline__ short8 ldsB(const unsigned short* Bsm, int k0, int px) {
    short8 f;
    #pragma unroll
    for (int e = 0; e < 8; ++e) f[e] = (short)Bsm[(k0 + e) * 66 + px];
    return f;
}

// ---- prep: fp32 input -> bf16 -------------------------------------------
__global__ void k_cvt_in(const float* __restrict__ in, unsigned short* __restrict__ out) {
    int i = blockIdx.x * 256 + threadIdx.x;
    float4 v = ((const float4*)in)[i];
    ushort4 o;
    o.x = f2bf(v.x); o.y = f2bf(v.y); o.z = f2bf(v.z); o.w = f2bf(v.w);
    ((ushort4*)out)[i] = o;
}

// ---- prep: weights -> bf16 fragment-ordered -----------------------------
// 1x1: dst[((kc*12+mf)*64+l)*8+e] = W[o][k], o=mf*16+(l&15), k=kc*32+(l>>4)*8+e
// conv: dst[(((tap*6+kc)*12+mf)*64+l)*8+e] = ws1[(o*192+c)*9+tap]
__global__ void k_prep_w(const float* __restrict__ w0, const float* __restrict__ w1,
                         const float* __restrict__ ws0, const float* __restrict__ wo,
                         const float* __restrict__ ws1,
                         unsigned short* __restrict__ w0f, unsigned short* __restrict__ w1f,
                         unsigned short* __restrict__ ws0xf, unsigned short* __restrict__ wof,
                         unsigned short* __restrict__ wc3f, float* __restrict__ gsum) {
    int i = blockIdx.x * 256 + threadIdx.x;
    if (i < 4*36864) {
        int which = i / 36864, j = i % 36864;
        int kc = j / 6144, r = j % 6144, mf = r / 512, r2 = r % 512;
        int l = r2 >> 3, e = r2 & 7;
        int o = mf*16 + (l & 15), k = kc*32 + ((l >> 4) << 3) + e;
        float v;
        unsigned short* dst;
        if (which == 0)      { v = w0[o*192 + k];  dst = w0f;   }
        else if (which == 1) { v = w1[o*192 + k];  dst = w1f;   }
        else if (which == 2) { v = ws0[o*384 + k]; dst = ws0xf; }
        else                 { v = wo[o*192 + k];  dst = wof;   }
        dst[j] = f2bf(v);
        return;
    }
    i -= 4*36864;
    if (i < 331776) {
        int tk = i / 6144, tap = tk / 6, kc = tk % 6;
        int r = i % 6144, mf = r / 512, r2 = r % 512;
        int l = r2 >> 3, e = r2 & 7;
        int o = mf*16 + (l & 15), c = kc*32 + ((l >> 4) << 3) + e;
        wc3f[i] = f2bf(ws1[(o*192 + c)*9 + tap]);
        return;
    }
    i -= 331776;
    if (i < 1536) gsum[i] = 0.f;
}

// ---- prep: t[b][m][o] = sum_c ws0[o][192+c] * center[b][m][c] -----------
__global__ void k_tcent(const float* __restrict__ ws0, const float* __restrict__ lc,
                        float* __restrict__ tc) {
    int m = blockIdx.x, b = blockIdx.y, o = threadIdx.x;
    __shared__ float cbuf[192];
    cbuf[o] = lc[(b*16 + m)*192 + o];
    __syncthreads();
    float a = 0.f;
    const float* wr = ws0 + o*384 + 192;
    for (int c = 0; c < 192; ++c) a += wr[c] * cbuf[c];
    tc[(b*16 + m)*192 + o] = a;
}

// ---- fused triple 1x1 GEMM: in -> h -> x -> y0 --------------------------
// wave-M-split: wave owns 48 output rows (3 m-frags); A from fragment-ordered
// global (coalesced, L2-hot); B tiles live in LDS (stride-66, conflict-free).
__global__ __launch_bounds__(256) void k_fused3(
    const unsigned short* __restrict__ inb,
    const unsigned short* __restrict__ w0f,
    const unsigned short* __restrict__ w1f,
    const unsigned short* __restrict__ ws0xf,
    const float* __restrict__ b0, const float* __restrict__ b1,
    const float* __restrict__ bs0,
    const float* __restrict__ tc, const int* __restrict__ mask,
    unsigned short* __restrict__ xg, unsigned short* __restrict__ y0g)
{
    const int b = blockIdx.y, n0 = blockIdx.x * 64;
    __shared__ unsigned short Bsm[192*66];
    __shared__ unsigned short Csm[192*66];
    const int tid = threadIdx.x, lane = tid & 63, wv = tid >> 6;
    const int li = lane & 15, kq = lane >> 4;

    // stage input tile [192 k][64 px] (uint4 global, 4x b32 LDS writes)
    {
        const unsigned short* src = inb + (size_t)b*192*PIX + n0;
        #pragma unroll
        for (int j = 0; j < 6; ++j) {
            int q = tid + 256*j, k = q >> 3, g = q & 7;
            uint4 v = *(const uint4*)(src + (size_t)k*PIX + g*8);
            unsigned* d = (unsigned*)(Bsm + k*66 + g*8);
            const unsigned* s = (const unsigned*)&v;
            d[0]=s[0]; d[1]=s[1]; d[2]=s[2]; d[3]=s[3];
        }
    }
    __syncthreads();

    f32x4 acc[3][4];

    // ---- GEMM A: h = lrelu(W0.in + b0) -> Csm
    #pragma unroll
    for (int m = 0; m < 3; ++m)
        #pragma unroll
        for (int n = 0; n < 4; ++n) acc[m][n] = {0.f,0.f,0.f,0.f};
    for (int kc = 0; kc < 6; ++kc) {
        short8 a[3];
        #pragma unroll
        for (int m = 0; m < 3; ++m)
            a[m] = *(const short8*)(w0f + ((kc*12 + wv*3 + m)*64 + lane)*8);
        #pragma unroll
        for (int n = 0; n < 4; ++n) {
            short8 fb = ldsB(Bsm, kc*32 + kq*8, n*16 + li);
            #pragma unroll
            for (int m = 0; m < 3; ++m)
                acc[m][n] = __builtin_amdgcn_mfma_f32_16x16x32_bf16(a[m], fb, acc[m][n], 0,0,0);
        }
    }
    #pragma unroll
    for (int m = 0; m < 3; ++m) {
        int o0 = (wv*3 + m)*16 + kq*4;
        #pragma unroll
        for (int n = 0; n < 4; ++n) {
            int px = n*16 + li;
            #pragma unroll
            for (int r = 0; r < 4; ++r) {
                float v = acc[m][n][r] + b0[o0 + r];
                v = v > 0.f ? v : 0.1f*v;
                Csm[(o0 + r)*66 + px] = f2bf(v);
            }
        }
    }
    __syncthreads();

    // ---- GEMM B: x = W1.h + b1 -> global x + Bsm (overwrite input tile)
    #pragma unroll
    for (int m = 0; m < 3; ++m)
        #pragma unroll
        for (int n = 0; n < 4; ++n) acc[m][n] = {0.f,0.f,0.f,0.f};
    for (int kc = 0; kc < 6; ++kc) {
        short8 a[3];
        #pragma unroll
        for (int m = 0; m < 3; ++m)
            a[m] = *(const short8*)(w1f + ((kc*12 + wv*3 + m)*64 + lane)*8);
        #pragma unroll
        for (int n = 0; n < 4; ++n) {
            short8 fb = ldsB(Csm, kc*32 + kq*8, n*16 + li);
            #pragma unroll
            for (int m = 0; m < 3; ++m)
                acc[m][n] = __builtin_amdgcn_mfma_f32_16x16x32_bf16(a[m], fb, acc[m][n], 0,0,0);
        }
    }
    #pragma unroll
    for (int m = 0; m < 3; ++m) {
        int o0 = (wv*3 + m)*16 + kq*4;
        #pragma unroll
        for (int n = 0; n < 4; ++n) {
            int px = n*16 + li;
            #pragma unroll
            for (int r = 0; r < 4; ++r) {
                float v = acc[m][n][r] + b1[o0 + r];
                unsigned short h = f2bf(v);
                Bsm[(o0 + r)*66 + px] = h;
                xg[((size_t)b*192 + o0 + r)*PIX + n0 + px] = h;
            }
        }
    }
    __syncthreads();

    // ---- GEMM C: y0 = lrelu(Ws0x.x + bs0 + tc[mask]) -> global
    #pragma unroll
    for (int m = 0; m < 3; ++m)
        #pragma unroll
        for (int n = 0; n < 4; ++n) acc[m][n] = {0.f,0.f,0.f,0.f};
    for (int kc = 0; kc < 6; ++kc) {
        short8 a[3];
        #pragma unroll
        for (int m = 0; m < 3; ++m)
            a[m] = *(const short8*)(ws0xf + ((kc*12 + wv*3 + m)*64 + lane)*8);
        #pragma unroll
        for (int n = 0; n < 4; ++n) {
            short8 fb = ldsB(Bsm, kc*32 + kq*8, n*16 + li);
            #pragma unroll
            for (int m = 0; m < 3; ++m)
                acc[m][n] = __builtin_amdgcn_mfma_f32_16x16x32_bf16(a[m], fb, acc[m][n], 0,0,0);
        }
    }
    int mi_[4];
    #pragma unroll
    for (int n = 0; n < 4; ++n) mi_[n] = mask[b*PIX + n0 + n*16 + li];
    #pragma unroll
    for (int m = 0; m < 3; ++m) {
        int o0 = (wv*3 + m)*16 + kq*4;
        #pragma unroll
        for (int n = 0; n < 4; ++n) {
            int px = n*16 + li;
            const float* tcb = tc + (b*16 + mi_[n])*192;
            #pragma unroll
            for (int r = 0; r < 4; ++r) {
                float v = acc[m][n][r] + bs0[o0 + r] + tcb[o0 + r];
                v = v > 0.f ? v : 0.1f*v;
                y0g[((size_t)b*192 + o0 + r)*PIX + n0 + px] = f2bf(v);
            }
        }
    }
}

// ---- 3x3 conv: block=(h,b); B staged once per kc for all 3 rows+halo ----
__global__ __launch_bounds__(256) void k_conv3n(
    const unsigned short* __restrict__ wc3f,
    const unsigned short* __restrict__ y0,
    const float* __restrict__ bias,
    unsigned short* __restrict__ y1)
{
    const int b = blockIdx.y, h = blockIdx.x;
    __shared__ unsigned short Bs[3*32*66];   // [dr][k][wc], wc=w+1, halo at 0/65
    const int tid = threadIdx.x, lane = tid & 63, wv = tid >> 6;
    const int li = lane & 15, kq = lane >> 4;

    f32x4 acc[3][4];
    #pragma unroll
    for (int m = 0; m < 3; ++m)
        #pragma unroll
        for (int n = 0; n < 4; ++n) acc[m][n] = {0.f,0.f,0.f,0.f};

    // zero halo columns once (never overwritten by staging)
    if (tid < 96) Bs[tid*66] = 0;
    else if (tid < 192) Bs[(tid-96)*66 + 65] = 0;

    for (int kc = 0; kc < 6; ++kc) {
        // stage 3 rows x 32 k x 64 w (zeros for OOB rows)
        #pragma unroll
        for (int j = 0; j < 3; ++j) {
            int q = tid*3 + j;
            int dr = q >> 8, k = (q >> 3) & 31, w8 = (q & 7)*8;
            int hh = h + dr - 1;
            uint4 v = {0u,0u,0u,0u};
            if (hh >= 0 && hh < 64)
                v = *(const uint4*)(y0 + ((size_t)b*192 + kc*32 + k)*PIX + hh*64 + w8);
            const unsigned short* pv = (const unsigned short*)&v;
            unsigned short* dst = Bs + (dr*32 + k)*66 + 1 + w8;
            #pragma unroll
            for (int e = 0; e < 8; ++e) dst[e] = pv[e];
        }
        __syncthreads();

        #pragma unroll
        for (int tap = 0; tap < 9; ++tap) {
            const int dr = tap / 3, dc1 = tap % 3;   // dc+1
            short8 a[3];
            #pragma unroll
            for (int m = 0; m < 3; ++m)
                a[m] = *(const short8*)(wc3f + (((tap*6 + kc)*12 + wv*3 + m)*64 + lane)*8);
            #pragma unroll
            for (int n = 0; n < 4; ++n) {
                short8 fb = ldsB(Bs + dr*32*66, kq*8, n*16 + li + dc1);
                #pragma unroll
                for (int m = 0; m < 3; ++m)
                    acc[m][n] = __builtin_amdgcn_mfma_f32_16x16x32_bf16(a[m], fb, acc[m][n], 0,0,0);
            }
        }
        __syncthreads();
    }

    #pragma unroll
    for (int m = 0; m < 3; ++m) {
        int o0 = (wv*3 + m)*16 + kq*4;
        #pragma unroll
        for (int n = 0; n < 4; ++n) {
            int px = h*64 + n*16 + li;
            #pragma unroll
            for (int r = 0; r < 4; ++r) {
                float v = acc[m][n][r] + bias[o0 + r];
                v = v > 0.f ? v : 0.1f*v;
                y1[((size_t)b*192 + o0 + r)*PIX + px] = f2bf(v);
            }
        }
    }
}

// ---- fused depthwise-3x3 + dynamic conv + gate-sum; block=(c,b) plane ---
__global__ __launch_bounds__(256) void k_dwdyn2(
    const unsigned short* __restrict__ Y1,
    const unsigned short* __restrict__ X,
    const float* __restrict__ ws2,          // [192][9][9] = [c][j][tap]
    const float* __restrict__ bs2,          // [192*9]
    unsigned short* __restrict__ OP,
    float* __restrict__ gsum)               // [BSZ][192]
{
    const int c = blockIdx.x, b = blockIdx.y;
    __shared__ unsigned short ysm[4096];
    __shared__ unsigned short xsm[4096];
    __shared__ float wsm[81], bsm9[9], red[4];
    const int tid = threadIdx.x;
    const size_t cb = ((size_t)b*192 + c) * PIX;
    #pragma unroll
    for (int j = 0; j < 2; ++j) {
        int i = tid + 256*j;
        *(uint4*)(ysm + i*8) = *(const uint4*)(Y1 + cb + i*8);
        *(uint4*)(xsm + i*8) = *(const uint4*)(X  + cb + i*8);
    }
    if (tid < 81) wsm[tid] = ws2[c*81 + tid];
    else if (tid < 90) bsm9[tid-81] = bs2[c*9 + tid - 81];
    __syncthreads();

    float gacc = 0.f;
    for (int i = 0; i < 16; ++i) {
        int px = tid + 256*i, hh = px >> 6, ww = px & 63;
        float ksp[9];
        #pragma unroll
        for (int j = 0; j < 9; ++j) ksp[j] = bsm9[j];
        #pragma unroll
        for (int tap = 0; tap < 9; ++tap) {
            int h2 = hh + tap/3 - 1, w2 = ww + tap%3 - 1;
            float yv = ((unsigned)h2 < 64u && (unsigned)w2 < 64u)
                       ? bf2f(ysm[h2*64 + w2]) : 0.f;
            #pragma unroll
            for (int j = 0; j < 9; ++j) ksp[j] += yv * wsm[j*9 + tap];
        }
        float out = 0.f;
        #pragma unroll
        for (int j = 0; j < 9; ++j) {
            int h2 = hh + j/3 - 1, w2 = ww + j%3 - 1;
            float xv = ((unsigned)h2 < 64u && (unsigned)w2 < 64u)
                       ? bf2f(xsm[h2*64 + w2]) : 0.f;
            out += xv * ksp[j];
        }
        OP[cb + px] = f2bf(out);
        gacc += out;
    }
    #pragma unroll
    for (int off = 32; off > 0; off >>= 1) gacc += __shfl_down(gacc, off);
    if ((tid & 63) == 0) red[tid >> 6] = gacc;
    __syncthreads();
    if (tid == 0) gsum[b*192 + c] = red[0] + red[1] + red[2] + red[3];
}

// ---- SE gate ------------------------------------------------------------
__global__ void k_gate(const float* __restrict__ gsum,
                       const float* __restrict__ wc0, const float* __restrict__ bc0,
                       const float* __restrict__ wc1, const float* __restrict__ bc1,
                       float* __restrict__ gvec)
{
    const int b = blockIdx.x, t = threadIdx.x;
    __shared__ float mean[192], s1[192];
    mean[t] = gsum[b*192 + t] * (1.f/4096.f);
    __syncthreads();
    float a = bc0[t];
    const float* w = wc0 + t*192;
    for (int i = 0; i < 192; ++i) a += w[i] * mean[i];
    s1[t] = a > 0.f ? a : 0.1f * a;
    __syncthreads();
    float a2 = bc1[t];
    const float* w2 = wc1 + t*192;
    for (int i = 0; i < 192; ++i) a2 += w2[i] * s1[i];
    gvec[b*192 + t] = 1.f / (1.f + __expf(-a2));
}

// ---- final: out = Wo.(g*op) + bo + input --------------------------------
__global__ __launch_bounds__(256) void k_gemmo(
    const unsigned short* __restrict__ wof,
    const unsigned short* __restrict__ op,
    const float* __restrict__ bo,
    const float* __restrict__ gvec,
    const float* __restrict__ resid,
    float* __restrict__ out)
{
    const int b = blockIdx.y, n0 = blockIdx.x * 64;
    __shared__ unsigned short Bsm[192*66];
    const int tid = threadIdx.x, lane = tid & 63, wv = tid >> 6;
    const int li = lane & 15, kq = lane >> 4;

    {
        const unsigned short* src = op + (size_t)b*192*PIX + n0;
        #pragma unroll
        for (int j = 0; j < 6; ++j) {
            int q = tid + 256*j, k = q >> 3, g = q & 7;
            uint4 v = *(const uint4*)(src + (size_t)k*PIX + g*8);
            float gs = gvec[b*192 + k];
            unsigned short* pv = (unsigned short*)&v;
            #pragma unroll
            for (int e = 0; e < 8; ++e) pv[e] = f2bf(bf2f(pv[e]) * gs);
            unsigned* d = (unsigned*)(Bsm + k*66 + g*8);
            const unsigned* s = (const unsigned*)&v;
            d[0]=s[0]; d[1]=s[1]; d[2]=s[2]; d[3]=s[3];
        }
    }
    __syncthreads();

    f32x4 acc[3][4];
    #pragma unroll
    for (int m = 0; m < 3; ++m)
        #pragma unroll
        for (int n = 0; n < 4; ++n) acc[m][n] = {0.f,0.f,0.f,0.f};
    for (int kc = 0; kc < 6; ++kc) {
        short8 a[3];
        #pragma unroll
        for (int m = 0; m < 3; ++m)
            a[m] = *(const short8*)(wof + ((kc*12 + wv*3 + m)*64 + lane)*8);
        #pragma unroll
        for (int n = 0; n < 4; ++n) {
            short8 fb = ldsB(Bsm, kc*32 + kq*8, n*16 + li);
            #pragma unroll
            for (int m = 0; m < 3; ++m)
                acc[m][n] = __builtin_amdgcn_mfma_f32_16x16x32_bf16(a[m], fb, acc[m][n], 0,0,0);
        }
    }
    #pragma unroll
    for (int m = 0; m < 3; ++m) {
        int o0 = (wv*3 + m)*16 + kq*4;
        #pragma unroll
        for (int n = 0; n < 4; ++n) {
            int px = n*16 + li;
            #pragma unroll
            for (int r = 0; r < 4; ++r) {
                size_t idx = ((size_t)b*192 + o0 + r)*PIX + n0 + px;
                out[idx] = acc[m][n][r] + bo[o0 + r] + resid[idx];
            }
        }
    }
}

extern "C" void kernel_launch(void* const* d_in, const int* in_sizes, int n_in,
                              void* d_out, int out_size, void* d_ws, size_t ws_size,
                              hipStream_t stream)
{
    const float* input = (const float*)d_in[0];
    const float* lc    = (const float*)d_in[1];
    const int*   mask  = (const int*)d_in[2];
    const float* w0  = (const float*)d_in[3];
    const float* b0  = (const float*)d_in[4];
    const float* w1  = (const float*)d_in[5];
    const float* b1  = (const float*)d_in[6];
    const float* ws0 = (const float*)d_in[7];
    const float* bs0 = (const float*)d_in[8];
    const float* ws1 = (const float*)d_in[9];
    const float* bs1 = (const float*)d_in[10];
    const float* ws2 = (const float*)d_in[11];
    const float* bs2 = (const float*)d_in[12];
    const float* wc0 = (const float*)d_in[13];
    const float* bc0 = (const float*)d_in[14];
    const float* wc1 = (const float*)d_in[15];
    const float* bc1 = (const float*)d_in[16];
    const float* wo  = (const float*)d_in[17];
    const float* bo  = (const float*)d_in[18];

    char* ws = (char*)d_ws;
    size_t off = 0;
    auto alloc = [&](size_t bytes) {
        void* p = ws + off; off = (off + bytes + 255) & ~(size_t)255; return p;
    };
    const size_t act_b = (size_t)BSZ * CH * PIX * 2;
    unsigned short* in_bf = (unsigned short*)alloc(act_b);
    unsigned short* x_bf  = (unsigned short*)alloc(act_b);
    unsigned short* y0_bf = (unsigned short*)alloc(act_b);
    unsigned short* y1_bf = (unsigned short*)alloc(act_b);
    unsigned short* op_bf = (unsigned short*)alloc(act_b);
    unsigned short* w0f   = (unsigned short*)alloc(36864*2);
    unsigned short* w1f   = (unsigned short*)alloc(36864*2);
    unsigned short* ws0xf = (unsigned short*)alloc(36864*2);
    unsigned short* wof   = (unsigned short*)alloc(36864*2);
    unsigned short* wc3f  = (unsigned short*)alloc(331776*2);
    float* tc   = (float*)alloc(8*16*192*4);
    float* gsum = (float*)alloc(1536*4);
    float* gvec = (float*)alloc(1536*4);

    k_cvt_in<<<6144, 256, 0, stream>>>(input, in_bf);
    k_prep_w<<<1878, 256, 0, stream>>>(w0, w1, ws0, wo, ws1, w0f, w1f, ws0xf, wof, wc3f, gsum);
    k_tcent<<<dim3(16, 8), 192, 0, stream>>>(ws0, lc, tc);

    dim3 gg(64, 8);
    k_fused3<<<gg, 256, 0, stream>>>(in_bf, w0f, w1f, ws0xf, b0, b1, bs0, tc, mask, x_bf, y0_bf);
    k_conv3n<<<gg, 256, 0, stream>>>(wc3f, y0_bf, bs1, y1_bf);
    k_dwdyn2<<<dim3(192, 8), 256, 0, stream>>>(y1_bf, x_bf, ws2, bs2, op_bf, gsum);
    k_gate<<<8, 192, 0, stream>>>(gsum, wc0, bc0, wc1, bc1, gvec);
    k_gemmo<<<gg, 256, 0, stream>>>(wof, op_bf, bo, gvec, input, (float*)d_out);
}

// Round 5
// 232.167 us; speedup vs baseline: 1.7702x; 1.0633x over previous
//
#include <hip/hip_runtime.h>
#include <hip/hip_bf16.h>

#define CH   192
#define PIX  4096   // 64*64 per image
#define BSZ  8

using f32x4  = __attribute__((ext_vector_type(4))) float;
using short8 = __attribute__((ext_vector_type(8))) short;

__device__ __forceinline__ float bf2f(unsigned short u) {
    union { unsigned u32; float f; } x; x.u32 = ((unsigned)u) << 16; return x.f;
}
__device__ __forceinline__ unsigned short f2bf(float f) {
    union { float f; unsigned u; } x; x.f = f;
    unsigned u = x.u;
    unsigned r = (u + 0x7FFFu + ((u >> 16) & 1u)) >> 16;  // RNE
    return (unsigned short)r;
}

// scalar-gather B fragment: 8 ushorts at rows k0..k0+7 (stride ST), col px
__device__ __forceinline__ short8 ldsBs(const unsigned short* B, int ST, int k0, int px) {
    short8 f;
    #pragma unroll
    for (int e = 0; e < 8; ++e) f[e] = (short)B[(k0 + e) * ST + px];
    return f;
}

// ---- prep: weights -> bf16 fragment-ordered -----------------------------
// 1x1: dst[((kc*12+mf)*64+l)*8+e] = W[o][k], o=mf*16+(l&15), k=kc*32+(l>>4)*8+e
// conv: dst[(((tap*6+kc)*12+mf)*64+l)*8+e] = ws1[(o*192+c)*9+tap]
__global__ void k_prep_w(const float* __restrict__ w0, const float* __restrict__ w1,
                         const float* __restrict__ ws0, const float* __restrict__ wo,
                         const float* __restrict__ ws1,
                         unsigned short* __restrict__ w0f, unsigned short* __restrict__ w1f,
                         unsigned short* __restrict__ ws0xf, unsigned short* __restrict__ wof,
                         unsigned short* __restrict__ wc3f, float* __restrict__ gsum) {
    int i = blockIdx.x * 256 + threadIdx.x;
    if (i < 4*36864) {
        int which = i / 36864, j = i % 36864;
        int kc = j / 6144, r = j % 6144, mf = r / 512, r2 = r % 512;
        int l = r2 >> 3, e = r2 & 7;
        int o = mf*16 + (l & 15), k = kc*32 + ((l >> 4) << 3) + e;
        float v;
        unsigned short* dst;
        if (which == 0)      { v = w0[o*192 + k];  dst = w0f;   }
        else if (which == 1) { v = w1[o*192 + k];  dst = w1f;   }
        else if (which == 2) { v = ws0[o*384 + k]; dst = ws0xf; }
        else                 { v = wo[o*192 + k];  dst = wof;   }
        dst[j] = f2bf(v);
        return;
    }
    i -= 4*36864;
    if (i < 331776) {
        int tk = i / 6144, tap = tk / 6, kc = tk % 6;
        int r = i % 6144, mf = r / 512, r2 = r % 512;
        int l = r2 >> 3, e = r2 & 7;
        int o = mf*16 + (l & 15), c = kc*32 + ((l >> 4) << 3) + e;
        wc3f[i] = f2bf(ws1[(o*192 + c)*9 + tap]);
        return;
    }
    i -= 331776;
    if (i < 1536) gsum[i] = 0.f;
}

// ---- prep: t[b][m][o] = sum_c ws0[o][192+c] * center[b][m][c] -----------
__global__ void k_tcent(const float* __restrict__ ws0, const float* __restrict__ lc,
                        float* __restrict__ tc) {
    int m = blockIdx.x, b = blockIdx.y, o = threadIdx.x;
    __shared__ float cbuf[192];
    cbuf[o] = lc[(b*16 + m)*192 + o];
    __syncthreads();
    float a = 0.f;
    const float* wr = ws0 + o*384 + 192;
    for (int c = 0; c < 192; ++c) a += wr[c] * cbuf[c];
    tc[(b*16 + m)*192 + o] = a;
}

// ---- fused triple 1x1 GEMM: input(fp32) -> h -> x -> y0T ----------------
// y0T layout: [b][px][c] so conv3t can stage px-major with b128 reads.
__global__ __launch_bounds__(256) void k_fused3(
    const float* __restrict__ input,
    const unsigned short* __restrict__ w0f,
    const unsigned short* __restrict__ w1f,
    const unsigned short* __restrict__ ws0xf,
    const float* __restrict__ b0, const float* __restrict__ b1,
    const float* __restrict__ bs0,
    const float* __restrict__ tc, const int* __restrict__ mask,
    unsigned short* __restrict__ xg, unsigned short* __restrict__ y0t)
{
    const int b = blockIdx.y, n0 = blockIdx.x * 64;
    __shared__ unsigned short Bsm[192*66];   // k-major, stride 66
    __shared__ unsigned short Csm[192*67];   // k-major stride 67; reused px-major [64][200]
    const int tid = threadIdx.x, lane = tid & 63, wv = tid >> 6;
    const int li = lane & 15, kq = lane >> 4;

    // stage input tile [192 k][64 px], fp32 -> bf16 in-register
    {
        const float* src = input + (size_t)b*192*PIX + n0;
        #pragma unroll
        for (int j = 0; j < 6; ++j) {
            int q = tid + 256*j, k = q >> 3, g = (q & 7)*8;
            float4 v0 = *(const float4*)(src + (size_t)k*PIX + g);
            float4 v1 = *(const float4*)(src + (size_t)k*PIX + g + 4);
            unsigned d0 = f2bf(v0.x) | ((unsigned)f2bf(v0.y) << 16);
            unsigned d1 = f2bf(v0.z) | ((unsigned)f2bf(v0.w) << 16);
            unsigned d2 = f2bf(v1.x) | ((unsigned)f2bf(v1.y) << 16);
            unsigned d3 = f2bf(v1.z) | ((unsigned)f2bf(v1.w) << 16);
            unsigned* d = (unsigned*)(Bsm + k*66 + g);
            d[0]=d0; d[1]=d1; d[2]=d2; d[3]=d3;
        }
    }
    __syncthreads();

    f32x4 acc[3][4];

    // ---- GEMM A: h = lrelu(W0.in + b0) -> Csm (stride 67)
    #pragma unroll
    for (int m = 0; m < 3; ++m)
        #pragma unroll
        for (int n = 0; n < 4; ++n) acc[m][n] = {0.f,0.f,0.f,0.f};
    for (int kc = 0; kc < 6; ++kc) {
        short8 a[3];
        #pragma unroll
        for (int m = 0; m < 3; ++m)
            a[m] = *(const short8*)(w0f + ((kc*12 + wv*3 + m)*64 + lane)*8);
        #pragma unroll
        for (int n = 0; n < 4; ++n) {
            short8 fb = ldsBs(Bsm, 66, kc*32 + kq*8, n*16 + li);
            #pragma unroll
            for (int m = 0; m < 3; ++m)
                acc[m][n] = __builtin_amdgcn_mfma_f32_16x16x32_bf16(a[m], fb, acc[m][n], 0,0,0);
        }
    }
    #pragma unroll
    for (int m = 0; m < 3; ++m) {
        int o0 = (wv*3 + m)*16 + kq*4;
        #pragma unroll
        for (int n = 0; n < 4; ++n) {
            int px = n*16 + li;
            #pragma unroll
            for (int r = 0; r < 4; ++r) {
                float v = acc[m][n][r] + b0[o0 + r];
                v = v > 0.f ? v : 0.1f*v;
                Csm[(o0 + r)*67 + px] = f2bf(v);
            }
        }
    }
    __syncthreads();

    // ---- GEMM B: x = W1.h + b1 -> global xg + Bsm (overwrite input tile)
    #pragma unroll
    for (int m = 0; m < 3; ++m)
        #pragma unroll
        for (int n = 0; n < 4; ++n) acc[m][n] = {0.f,0.f,0.f,0.f};
    for (int kc = 0; kc < 6; ++kc) {
        short8 a[3];
        #pragma unroll
        for (int m = 0; m < 3; ++m)
            a[m] = *(const short8*)(w1f + ((kc*12 + wv*3 + m)*64 + lane)*8);
        #pragma unroll
        for (int n = 0; n < 4; ++n) {
            short8 fb = ldsBs(Csm, 67, kc*32 + kq*8, n*16 + li);
            #pragma unroll
            for (int m = 0; m < 3; ++m)
                acc[m][n] = __builtin_amdgcn_mfma_f32_16x16x32_bf16(a[m], fb, acc[m][n], 0,0,0);
        }
    }
    __syncthreads();   // all reads of Csm(h) done before GEMM C reuses it
    #pragma unroll
    for (int m = 0; m < 3; ++m) {
        int o0 = (wv*3 + m)*16 + kq*4;
        #pragma unroll
        for (int n = 0; n < 4; ++n) {
            int px = n*16 + li;
            #pragma unroll
            for (int r = 0; r < 4; ++r) {
                float v = acc[m][n][r] + b1[o0 + r];
                unsigned short h = f2bf(v);
                Bsm[(o0 + r)*66 + px] = h;
                xg[((size_t)b*192 + o0 + r)*PIX + n0 + px] = h;
            }
        }
    }
    __syncthreads();

    // ---- GEMM C: y0 = lrelu(Ws0x.x + bs0 + tc[mask]) -> Csm px-major -> y0T
    #pragma unroll
    for (int m = 0; m < 3; ++m)
        #pragma unroll
        for (int n = 0; n < 4; ++n) acc[m][n] = {0.f,0.f,0.f,0.f};
    for (int kc = 0; kc < 6; ++kc) {
        short8 a[3];
        #pragma unroll
        for (int m = 0; m < 3; ++m)
            a[m] = *(const short8*)(ws0xf + ((kc*12 + wv*3 + m)*64 + lane)*8);
        #pragma unroll
        for (int n = 0; n < 4; ++n) {
            short8 fb = ldsBs(Bsm, 66, kc*32 + kq*8, n*16 + li);
            #pragma unroll
            for (int m = 0; m < 3; ++m)
                acc[m][n] = __builtin_amdgcn_mfma_f32_16x16x32_bf16(a[m], fb, acc[m][n], 0,0,0);
        }
    }
    int mi_[4];
    #pragma unroll
    for (int n = 0; n < 4; ++n) mi_[n] = mask[b*PIX + n0 + n*16 + li];
    #pragma unroll
    for (int m = 0; m < 3; ++m) {
        int o0 = (wv*3 + m)*16 + kq*4;
        #pragma unroll
        for (int n = 0; n < 4; ++n) {
            int px = n*16 + li;
            const float* tcb = tc + (b*16 + mi_[n])*192;
            ushort4 w;
            unsigned short* wp = (unsigned short*)&w;
            #pragma unroll
            for (int r = 0; r < 4; ++r) {
                float v = acc[m][n][r] + bs0[o0 + r] + tcb[o0 + r];
                v = v > 0.f ? v : 0.1f*v;
                wp[r] = f2bf(v);
            }
            *(ushort4*)(Csm + px*200 + o0) = w;   // px-major [64][200]
        }
    }
    __syncthreads();
    // coalesced y0T store: [b][n0+px][c]
    #pragma unroll
    for (int j = 0; j < 6; ++j) {
        int u = tid + 256*j;           // 1536 units = 64 px * 24 chunks
        int px = u / 24, chunk = u % 24;
        uint4 v = *(const uint4*)(Csm + px*200 + chunk*8);
        *(uint4*)(y0t + ((size_t)(b*4096 + n0 + px))*192 + chunk*8) = v;
    }
}

// ---- 3x3 conv: 8 waves (4 M-split x 2 N-split); px-major LDS, b128 frags
__global__ __launch_bounds__(512) void k_conv3t(
    const unsigned short* __restrict__ wc3f,
    const unsigned short* __restrict__ y0t,   // [b][4096 px][192 c]
    const float* __restrict__ bias,
    unsigned short* __restrict__ y1)          // [b][c][4096 px]
{
    const int b = blockIdx.y, h = blockIdx.x;
    __shared__ unsigned short Bs[3*66*40];    // [dr][pxl][40 shorts], 80B rows (16B-aligned)
    const int tid = threadIdx.x, lane = tid & 63, wv = tid >> 6;
    const int li = lane & 15, kq = lane >> 4;
    const int mw = wv >> 1, nh = wv & 1;      // M-quarter, N-half

    f32x4 acc[3][2];
    #pragma unroll
    for (int m = 0; m < 3; ++m)
        #pragma unroll
        for (int nn = 0; nn < 2; ++nn) acc[m][nn] = {0.f,0.f,0.f,0.f};

    for (int kc = 0; kc < 6; ++kc) {
        // stage 3 rows x 66 px (incl. zero halo) x 32 c
        for (int u = tid; u < 792; u += 512) {
            int row = u >> 2, chunk = u & 3;
            int dr = row / 66, pxl = row % 66;
            int hh = h + dr - 1, pxg = pxl - 1;
            uint4 v = {0u,0u,0u,0u};
            if ((unsigned)hh < 64u && (unsigned)pxg < 64u)
                v = *(const uint4*)(y0t + ((size_t)(b*4096 + hh*64 + pxg))*192 + kc*32 + chunk*8);
            *(uint4*)((char*)Bs + row*80 + chunk*16) = v;
        }
        __syncthreads();

        #pragma unroll
        for (int tap = 0; tap < 9; ++tap) {
            const int dr = tap / 3, dc1 = tap % 3;
            short8 a[3];
            #pragma unroll
            for (int m = 0; m < 3; ++m)
                a[m] = *(const short8*)(wc3f + (((tap*6 + kc)*12 + mw*3 + m)*64 + lane)*8);
            #pragma unroll
            for (int nn = 0; nn < 2; ++nn) {
                int pxi = nh*32 + nn*16 + li + dc1;
                short8 fb = *(const short8*)((const char*)Bs + (dr*66 + pxi)*80 + kq*16);
                #pragma unroll
                for (int m = 0; m < 3; ++m)
                    acc[m][nn] = __builtin_amdgcn_mfma_f32_16x16x32_bf16(a[m], fb, acc[m][nn], 0,0,0);
            }
        }
        __syncthreads();
    }

    #pragma unroll
    for (int m = 0; m < 3; ++m) {
        int o0 = (mw*3 + m)*16 + kq*4;
        #pragma unroll
        for (int nn = 0; nn < 2; ++nn) {
            int px = h*64 + nh*32 + nn*16 + li;
            #pragma unroll
            for (int r = 0; r < 4; ++r) {
                float v = acc[m][nn][r] + bias[o0 + r];
                v = v > 0.f ? v : 0.1f*v;
                y1[((size_t)b*192 + o0 + r)*PIX + px] = f2bf(v);
            }
        }
    }
}

// ---- fused depthwise-3x3 + dynamic conv + gate-sum; block=(c,b) plane ---
__global__ __launch_bounds__(256) void k_dwdyn2(
    const unsigned short* __restrict__ Y1,
    const unsigned short* __restrict__ X,
    const float* __restrict__ ws2,          // [192][9][9] = [c][j][tap]
    const float* __restrict__ bs2,          // [192*9]
    unsigned short* __restrict__ OP,
    float* __restrict__ gsum)               // [BSZ][192]
{
    const int c = blockIdx.x, b = blockIdx.y;
    __shared__ unsigned short ysm[4096];
    __shared__ unsigned short xsm[4096];
    __shared__ float wsm[81], bsm9[9], red[4];
    const int tid = threadIdx.x;
    const size_t cb = ((size_t)b*192 + c) * PIX;
    #pragma unroll
    for (int j = 0; j < 2; ++j) {
        int i = tid + 256*j;
        *(uint4*)(ysm + i*8) = *(const uint4*)(Y1 + cb + i*8);
        *(uint4*)(xsm + i*8) = *(const uint4*)(X  + cb + i*8);
    }
    if (tid < 81) wsm[tid] = ws2[c*81 + tid];
    else if (tid < 90) bsm9[tid-81] = bs2[c*9 + tid - 81];
    __syncthreads();

    float gacc = 0.f;
    for (int i = 0; i < 16; ++i) {
        int px = tid + 256*i, hh = px >> 6, ww = px & 63;
        float ksp[9];
        #pragma unroll
        for (int j = 0; j < 9; ++j) ksp[j] = bsm9[j];
        #pragma unroll
        for (int tap = 0; tap < 9; ++tap) {
            int h2 = hh + tap/3 - 1, w2 = ww + tap%3 - 1;
            float yv = ((unsigned)h2 < 64u && (unsigned)w2 < 64u)
                       ? bf2f(ysm[h2*64 + w2]) : 0.f;
            #pragma unroll
            for (int j = 0; j < 9; ++j) ksp[j] += yv * wsm[j*9 + tap];
        }
        float out = 0.f;
        #pragma unroll
        for (int j = 0; j < 9; ++j) {
            int h2 = hh + j/3 - 1, w2 = ww + j%3 - 1;
            float xv = ((unsigned)h2 < 64u && (unsigned)w2 < 64u)
                       ? bf2f(xsm[h2*64 + w2]) : 0.f;
            out += xv * ksp[j];
        }
        OP[cb + px] = f2bf(out);
        gacc += out;
    }
    #pragma unroll
    for (int off = 32; off > 0; off >>= 1) gacc += __shfl_down(gacc, off);
    if ((tid & 63) == 0) red[tid >> 6] = gacc;
    __syncthreads();
    if (tid == 0) gsum[b*192 + c] = red[0] + red[1] + red[2] + red[3];
}

// ---- SE gate ------------------------------------------------------------
__global__ void k_gate(const float* __restrict__ gsum,
                       const float* __restrict__ wc0, const float* __restrict__ bc0,
                       const float* __restrict__ wc1, const float* __restrict__ bc1,
                       float* __restrict__ gvec)
{
    const int b = blockIdx.x, t = threadIdx.x;
    __shared__ float mean[192], s1[192];
    mean[t] = gsum[b*192 + t] * (1.f/4096.f);
    __syncthreads();
    float a = bc0[t];
    const float* w = wc0 + t*192;
    for (int i = 0; i < 192; ++i) a += w[i] * mean[i];
    s1[t] = a > 0.f ? a : 0.1f * a;
    __syncthreads();
    float a2 = bc1[t];
    const float* w2 = wc1 + t*192;
    for (int i = 0; i < 192; ++i) a2 += w2[i] * s1[i];
    gvec[b*192 + t] = 1.f / (1.f + __expf(-a2));
}

// ---- final: out = Wo.(g*op) + bo + input --------------------------------
__global__ __launch_bounds__(256) void k_gemmo(
    const unsigned short* __restrict__ wof,
    const unsigned short* __restrict__ op,
    const float* __restrict__ bo,
    const float* __restrict__ gvec,
    const float* __restrict__ resid,
    float* __restrict__ out)
{
    const int b = blockIdx.y, n0 = blockIdx.x * 64;
    __shared__ unsigned short Bsm[192*66];
    const int tid = threadIdx.x, lane = tid & 63, wv = tid >> 6;
    const int li = lane & 15, kq = lane >> 4;

    {
        const unsigned short* src = op + (size_t)b*192*PIX + n0;
        #pragma unroll
        for (int j = 0; j < 6; ++j) {
            int q = tid + 256*j, k = q >> 3, g = (q & 7) * 8;
            uint4 v = *(const uint4*)(src + (size_t)k*PIX + g);
            float gs = gvec[b*192 + k];
            unsigned short* pv = (unsigned short*)&v;
            #pragma unroll
            for (int e = 0; e < 8; ++e) pv[e] = f2bf(bf2f(pv[e]) * gs);
            unsigned* d = (unsigned*)(Bsm + k*66 + g);
            const unsigned* s = (const unsigned*)&v;
            d[0]=s[0]; d[1]=s[1]; d[2]=s[2]; d[3]=s[3];
        }
    }
    __syncthreads();

    f32x4 acc[3][4];
    #pragma unroll
    for (int m = 0; m < 3; ++m)
        #pragma unroll
        for (int n = 0; n < 4; ++n) acc[m][n] = {0.f,0.f,0.f,0.f};
    for (int kc = 0; kc < 6; ++kc) {
        short8 a[3];
        #pragma unroll
        for (int m = 0; m < 3; ++m)
            a[m] = *(const short8*)(wof + ((kc*12 + wv*3 + m)*64 + lane)*8);
        #pragma unroll
        for (int n = 0; n < 4; ++n) {
            short8 fb = ldsBs(Bsm, 66, kc*32 + kq*8, n*16 + li);
            #pragma unroll
            for (int m = 0; m < 3; ++m)
                acc[m][n] = __builtin_amdgcn_mfma_f32_16x16x32_bf16(a[m], fb, acc[m][n], 0,0,0);
        }
    }
    #pragma unroll
    for (int m = 0; m < 3; ++m) {
        int o0 = (wv*3 + m)*16 + kq*4;
        #pragma unroll
        for (int n = 0; n < 4; ++n) {
            int px = n*16 + li;
            #pragma unroll
            for (int r = 0; r < 4; ++r) {
                size_t idx = ((size_t)b*192 + o0 + r)*PIX + n0 + px;
                out[idx] = acc[m][n][r] + bo[o0 + r] + resid[idx];
            }
        }
    }
}

extern "C" void kernel_launch(void* const* d_in, const int* in_sizes, int n_in,
                              void* d_out, int out_size, void* d_ws, size_t ws_size,
                              hipStream_t stream)
{
    const float* input = (const float*)d_in[0];
    const float* lc    = (const float*)d_in[1];
    const int*   mask  = (const int*)d_in[2];
    const float* w0  = (const float*)d_in[3];
    const float* b0  = (const float*)d_in[4];
    const float* w1  = (const float*)d_in[5];
    const float* b1  = (const float*)d_in[6];
    const float* ws0 = (const float*)d_in[7];
    const float* bs0 = (const float*)d_in[8];
    const float* ws1 = (const float*)d_in[9];
    const float* bs1 = (const float*)d_in[10];
    const float* ws2 = (const float*)d_in[11];
    const float* bs2 = (const float*)d_in[12];
    const float* wc0 = (const float*)d_in[13];
    const float* bc0 = (const float*)d_in[14];
    const float* wc1 = (const float*)d_in[15];
    const float* bc1 = (const float*)d_in[16];
    const float* wo  = (const float*)d_in[17];
    const float* bo  = (const float*)d_in[18];

    char* ws = (char*)d_ws;
    size_t off = 0;
    auto alloc = [&](size_t bytes) {
        void* p = ws + off; off = (off + bytes + 255) & ~(size_t)255; return p;
    };
    const size_t act_b = (size_t)BSZ * CH * PIX * 2;
    unsigned short* x_bf  = (unsigned short*)alloc(act_b);
    unsigned short* y0t   = (unsigned short*)alloc(act_b);   // [b][px][c]
    unsigned short* y1_bf = (unsigned short*)alloc(act_b);
    unsigned short* op_bf = (unsigned short*)alloc(act_b);
    unsigned short* w0f   = (unsigned short*)alloc(36864*2);
    unsigned short* w1f   = (unsigned short*)alloc(36864*2);
    unsigned short* ws0xf = (unsigned short*)alloc(36864*2);
    unsigned short* wof   = (unsigned short*)alloc(36864*2);
    unsigned short* wc3f  = (unsigned short*)alloc(331776*2);
    float* tc   = (float*)alloc(8*16*192*4);
    float* gsum = (float*)alloc(1536*4);
    float* gvec = (float*)alloc(1536*4);

    k_prep_w<<<1878, 256, 0, stream>>>(w0, w1, ws0, wo, ws1, w0f, w1f, ws0xf, wof, wc3f, gsum);
    k_tcent<<<dim3(16, 8), 192, 0, stream>>>(ws0, lc, tc);

    dim3 gg(64, 8);
    k_fused3<<<gg, 256, 0, stream>>>(input, w0f, w1f, ws0xf, b0, b1, bs0, tc, mask, x_bf, y0t);
    k_conv3t<<<gg, 512, 0, stream>>>(wc3f, y0t, bs1, y1_bf);
    k_dwdyn2<<<dim3(192, 8), 256, 0, stream>>>(y1_bf, x_bf, ws2, bs2, op_bf, gsum);
    k_gate<<<8, 192, 0, stream>>>(gsum, wc0, bc0, wc1, bc1, gvec);
    k_gemmo<<<gg, 256, 0, stream>>>(wof, op_bf, bo, gvec, input, (float*)d_out);
}

// Round 6
// 229.201 us; speedup vs baseline: 1.7931x; 1.0129x over previous
//
#include <hip/hip_runtime.h>
#include <hip/hip_bf16.h>

#define CH   192
#define PIX  4096   // 64*64 per image
#define BSZ  8

using f32x4  = __attribute__((ext_vector_type(4))) float;
using short8 = __attribute__((ext_vector_type(8))) short;

__device__ __forceinline__ float bf2f(unsigned short u) {
    union { unsigned u32; float f; } x; x.u32 = ((unsigned)u) << 16; return x.f;
}
__device__ __forceinline__ unsigned short f2bf(float f) {
    union { float f; unsigned u; } x; x.f = f;
    unsigned u = x.u;
    unsigned r = (u + 0x7FFFu + ((u >> 16) & 1u)) >> 16;  // RNE
    return (unsigned short)r;
}

// scalar-gather B fragment: 8 ushorts at rows k0..k0+7 (stride ST), col px
__device__ __forceinline__ short8 ldsBs(const unsigned short* B, int ST, int k0, int px) {
    short8 f;
    #pragma unroll
    for (int e = 0; e < 8; ++e) f[e] = (short)B[(k0 + e) * ST + px];
    return f;
}

// ---- prep: weights -> bf16 fragment-ordered; + tc precompute ------------
// 1x1: dst[((kc*12+mf)*64+l)*8+e] = W[o][k], o=mf*16+(l&15), k=kc*32+(l>>4)*8+e
// conv: dst[(((tap*6+kc)*12+mf)*64+l)*8+e] = ws1[(o*192+c)*9+tap]
// tcent: tc[(b*16+m)*192+o] = sum_c ws0[o][192+c]*lc[b][m][c]
__global__ void k_prep_w(const float* __restrict__ w0, const float* __restrict__ w1,
                         const float* __restrict__ ws0, const float* __restrict__ wo,
                         const float* __restrict__ ws1, const float* __restrict__ lc,
                         unsigned short* __restrict__ w0f, unsigned short* __restrict__ w1f,
                         unsigned short* __restrict__ ws0xf, unsigned short* __restrict__ wof,
                         unsigned short* __restrict__ wc3f, float* __restrict__ tc) {
    int i = blockIdx.x * 256 + threadIdx.x;
    if (i < 4*36864) {
        int which = i / 36864, j = i % 36864;
        int kc = j / 6144, r = j % 6144, mf = r / 512, r2 = r % 512;
        int l = r2 >> 3, e = r2 & 7;
        int o = mf*16 + (l & 15), k = kc*32 + ((l >> 4) << 3) + e;
        float v;
        unsigned short* dst;
        if (which == 0)      { v = w0[o*192 + k];  dst = w0f;   }
        else if (which == 1) { v = w1[o*192 + k];  dst = w1f;   }
        else if (which == 2) { v = ws0[o*384 + k]; dst = ws0xf; }
        else                 { v = wo[o*192 + k];  dst = wof;   }
        dst[j] = f2bf(v);
        return;
    }
    i -= 4*36864;
    if (i < 331776) {
        int tk = i / 6144, tap = tk / 6, kc = tk % 6;
        int r = i % 6144, mf = r / 512, r2 = r % 512;
        int l = r2 >> 3, e = r2 & 7;
        int o = mf*16 + (l & 15), c = kc*32 + ((l >> 4) << 3) + e;
        wc3f[i] = f2bf(ws1[(o*192 + c)*9 + tap]);
        return;
    }
    i -= 331776;
    if (i < 24576) {
        int bm = i / 192, o = i % 192;
        const float* wr = ws0 + o*384 + 192;
        const float* cb = lc + bm*192;
        float a = 0.f;
        for (int c2 = 0; c2 < 192; ++c2) a += wr[c2] * cb[c2];
        tc[i] = a;
    }
}

// ---- fused triple 1x1 GEMM: input(fp32) -> h -> x -> y0T ----------------
// y0T layout: [b][px][c] so conv3t can stage px-major with b128 reads.
__global__ __launch_bounds__(256) void k_fused3(
    const float* __restrict__ input,
    const unsigned short* __restrict__ w0f,
    const unsigned short* __restrict__ w1f,
    const unsigned short* __restrict__ ws0xf,
    const float* __restrict__ b0, const float* __restrict__ b1,
    const float* __restrict__ bs0,
    const float* __restrict__ tc, const int* __restrict__ mask,
    unsigned short* __restrict__ xg, unsigned short* __restrict__ y0t)
{
    const int b = blockIdx.y, n0 = blockIdx.x * 64;
    __shared__ unsigned short Bsm[192*66];   // k-major, stride 66
    __shared__ unsigned short Csm[192*67];   // k-major stride 67; reused px-major [64][200]
    const int tid = threadIdx.x, lane = tid & 63, wv = tid >> 6;
    const int li = lane & 15, kq = lane >> 4;

    // stage input tile [192 k][64 px], fp32 -> bf16 in-register
    {
        const float* src = input + (size_t)b*192*PIX + n0;
        #pragma unroll
        for (int j = 0; j < 6; ++j) {
            int q = tid + 256*j, k = q >> 3, g = (q & 7)*8;
            float4 v0 = *(const float4*)(src + (size_t)k*PIX + g);
            float4 v1 = *(const float4*)(src + (size_t)k*PIX + g + 4);
            unsigned d0 = f2bf(v0.x) | ((unsigned)f2bf(v0.y) << 16);
            unsigned d1 = f2bf(v0.z) | ((unsigned)f2bf(v0.w) << 16);
            unsigned d2 = f2bf(v1.x) | ((unsigned)f2bf(v1.y) << 16);
            unsigned d3 = f2bf(v1.z) | ((unsigned)f2bf(v1.w) << 16);
            unsigned* d = (unsigned*)(Bsm + k*66 + g);
            d[0]=d0; d[1]=d1; d[2]=d2; d[3]=d3;
        }
    }
    __syncthreads();

    f32x4 acc[3][4];

    // ---- GEMM A: h = lrelu(W0.in + b0) -> Csm (stride 67)
    #pragma unroll
    for (int m = 0; m < 3; ++m)
        #pragma unroll
        for (int n = 0; n < 4; ++n) acc[m][n] = {0.f,0.f,0.f,0.f};
    for (int kc = 0; kc < 6; ++kc) {
        short8 a[3];
        #pragma unroll
        for (int m = 0; m < 3; ++m)
            a[m] = *(const short8*)(w0f + ((kc*12 + wv*3 + m)*64 + lane)*8);
        #pragma unroll
        for (int n = 0; n < 4; ++n) {
            short8 fb = ldsBs(Bsm, 66, kc*32 + kq*8, n*16 + li);
            #pragma unroll
            for (int m = 0; m < 3; ++m)
                acc[m][n] = __builtin_amdgcn_mfma_f32_16x16x32_bf16(a[m], fb, acc[m][n], 0,0,0);
        }
    }
    #pragma unroll
    for (int m = 0; m < 3; ++m) {
        int o0 = (wv*3 + m)*16 + kq*4;
        #pragma unroll
        for (int n = 0; n < 4; ++n) {
            int px = n*16 + li;
            #pragma unroll
            for (int r = 0; r < 4; ++r) {
                float v = acc[m][n][r] + b0[o0 + r];
                v = v > 0.f ? v : 0.1f*v;
                Csm[(o0 + r)*67 + px] = f2bf(v);
            }
        }
    }
    __syncthreads();

    // ---- GEMM B: x = W1.h + b1 -> global xg + Bsm (overwrite input tile)
    #pragma unroll
    for (int m = 0; m < 3; ++m)
        #pragma unroll
        for (int n = 0; n < 4; ++n) acc[m][n] = {0.f,0.f,0.f,0.f};
    for (int kc = 0; kc < 6; ++kc) {
        short8 a[3];
        #pragma unroll
        for (int m = 0; m < 3; ++m)
            a[m] = *(const short8*)(w1f + ((kc*12 + wv*3 + m)*64 + lane)*8);
        #pragma unroll
        for (int n = 0; n < 4; ++n) {
            short8 fb = ldsBs(Csm, 67, kc*32 + kq*8, n*16 + li);
            #pragma unroll
            for (int m = 0; m < 3; ++m)
                acc[m][n] = __builtin_amdgcn_mfma_f32_16x16x32_bf16(a[m], fb, acc[m][n], 0,0,0);
        }
    }
    __syncthreads();   // all reads of Csm(h) done before GEMM C reuses it
    #pragma unroll
    for (int m = 0; m < 3; ++m) {
        int o0 = (wv*3 + m)*16 + kq*4;
        #pragma unroll
        for (int n = 0; n < 4; ++n) {
            int px = n*16 + li;
            #pragma unroll
            for (int r = 0; r < 4; ++r) {
                float v = acc[m][n][r] + b1[o0 + r];
                unsigned short h = f2bf(v);
                Bsm[(o0 + r)*66 + px] = h;
                xg[((size_t)b*192 + o0 + r)*PIX + n0 + px] = h;
            }
        }
    }
    __syncthreads();

    // ---- GEMM C: y0 = lrelu(Ws0x.x + bs0 + tc[mask]) -> Csm px-major -> y0T
    #pragma unroll
    for (int m = 0; m < 3; ++m)
        #pragma unroll
        for (int n = 0; n < 4; ++n) acc[m][n] = {0.f,0.f,0.f,0.f};
    for (int kc = 0; kc < 6; ++kc) {
        short8 a[3];
        #pragma unroll
        for (int m = 0; m < 3; ++m)
            a[m] = *(const short8*)(ws0xf + ((kc*12 + wv*3 + m)*64 + lane)*8);
        #pragma unroll
        for (int n = 0; n < 4; ++n) {
            short8 fb = ldsBs(Bsm, 66, kc*32 + kq*8, n*16 + li);
            #pragma unroll
            for (int m = 0; m < 3; ++m)
                acc[m][n] = __builtin_amdgcn_mfma_f32_16x16x32_bf16(a[m], fb, acc[m][n], 0,0,0);
        }
    }
    int mi_[4];
    #pragma unroll
    for (int n = 0; n < 4; ++n) mi_[n] = mask[b*PIX + n0 + n*16 + li];
    #pragma unroll
    for (int m = 0; m < 3; ++m) {
        int o0 = (wv*3 + m)*16 + kq*4;
        #pragma unroll
        for (int n = 0; n < 4; ++n) {
            int px = n*16 + li;
            const float* tcb = tc + (b*16 + mi_[n])*192;
            ushort4 w;
            unsigned short* wp = (unsigned short*)&w;
            #pragma unroll
            for (int r = 0; r < 4; ++r) {
                float v = acc[m][n][r] + bs0[o0 + r] + tcb[o0 + r];
                v = v > 0.f ? v : 0.1f*v;
                wp[r] = f2bf(v);
            }
            *(ushort4*)(Csm + px*200 + o0) = w;   // px-major [64][200]
        }
    }
    __syncthreads();
    // coalesced y0T store: [b][n0+px][c]
    #pragma unroll
    for (int j = 0; j < 6; ++j) {
        int u = tid + 256*j;           // 1536 units = 64 px * 24 chunks
        int px = u / 24, chunk = u % 24;
        uint4 v = *(const uint4*)(Csm + px*200 + chunk*8);
        *(uint4*)(y0t + ((size_t)(b*4096 + n0 + px))*192 + chunk*8) = v;
    }
}

// ---- 3x3 conv: 8 waves; double-buffered LDS, issue-early/commit-late ----
__global__ __launch_bounds__(512) void k_conv3t(
    const unsigned short* __restrict__ wc3f,
    const unsigned short* __restrict__ y0t,   // [b][4096 px][192 c]
    const float* __restrict__ bias,
    unsigned short* __restrict__ y1)          // [b][c][4096 px]
{
    const int b = blockIdx.y, h = blockIdx.x;
    __shared__ unsigned short Bs[2][3*66*40]; // [buf][dr][pxl][40 shorts], 80B rows
    const int tid = threadIdx.x, lane = tid & 63, wv = tid >> 6;
    const int li = lane & 15, kq = lane >> 4;
    const int mw = wv >> 1, nh = wv & 1;      // M-quarter, N-half

    // staging geometry: unit u covers LDS row u>>2 (dr,pxl), 16B chunk u&3
    const int u1 = tid + 512;
    const int r0 = tid >> 2,  c0 = tid & 3;
    const int dr0 = r0/66, px0g = r0%66 - 1, hh0 = h + dr0 - 1;
    const bool ok0 = ((unsigned)hh0 < 64u) & ((unsigned)px0g < 64u);
    const size_t s0 = ok0 ? ((size_t)(b*4096 + hh0*64 + px0g))*192 + c0*8 : 0;
    const int o0f = r0*80 + c0*16;
    const int r1 = u1 >> 2,  c1 = u1 & 3;
    const int dr1 = r1/66, px1g = r1%66 - 1, hh1 = h + dr1 - 1;
    const bool act1 = (u1 < 792);
    const bool ok1 = act1 & ((unsigned)hh1 < 64u) & ((unsigned)px1g < 64u);
    const size_t s1 = ok1 ? ((size_t)(b*4096 + hh1*64 + px1g))*192 + c1*8 : 0;
    const int o1f = r1*80 + c1*16;
    const uint4 zz = {0u,0u,0u,0u};

    uint4 v0, v1;
    // prologue: stage kc=0 into buf 0
    v0 = ok0 ? *(const uint4*)(y0t + s0) : zz;
    v1 = ok1 ? *(const uint4*)(y0t + s1) : zz;
    *(uint4*)((char*)Bs[0] + o0f) = v0;
    if (act1) *(uint4*)((char*)Bs[0] + o1f) = v1;
    __syncthreads();

    f32x4 acc[3][2];
    #pragma unroll
    for (int m = 0; m < 3; ++m)
        #pragma unroll
        for (int nn = 0; nn < 2; ++nn) acc[m][nn] = {0.f,0.f,0.f,0.f};

    for (int kc = 0; kc < 6; ++kc) {
        const int cur = kc & 1;
        if (kc < 5) {   // issue next-chunk loads early (hide under MFMA)
            v0 = ok0 ? *(const uint4*)(y0t + s0 + (kc+1)*32) : zz;
            v1 = ok1 ? *(const uint4*)(y0t + s1 + (kc+1)*32) : zz;
        }
        const unsigned short* Bc = Bs[cur];
        #pragma unroll
        for (int tap = 0; tap < 9; ++tap) {
            const int dr = tap / 3, dc1 = tap % 3;
            short8 a[3];
            #pragma unroll
            for (int m = 0; m < 3; ++m)
                a[m] = *(const short8*)(wc3f + (((tap*6 + kc)*12 + mw*3 + m)*64 + lane)*8);
            #pragma unroll
            for (int nn = 0; nn < 2; ++nn) {
                int pxi = nh*32 + nn*16 + li + dc1;
                short8 fb = *(const short8*)((const char*)Bc + (dr*66 + pxi)*80 + kq*16);
                #pragma unroll
                for (int m = 0; m < 3; ++m)
                    acc[m][nn] = __builtin_amdgcn_mfma_f32_16x16x32_bf16(a[m], fb, acc[m][nn], 0,0,0);
            }
        }
        if (kc < 5) {   // commit after compute; vmcnt wait lands here
            *(uint4*)((char*)Bs[cur^1] + o0f) = v0;
            if (act1) *(uint4*)((char*)Bs[cur^1] + o1f) = v1;
            __syncthreads();
        }
    }

    #pragma unroll
    for (int m = 0; m < 3; ++m) {
        int oo = (mw*3 + m)*16 + kq*4;
        #pragma unroll
        for (int nn = 0; nn < 2; ++nn) {
            int px = h*64 + nh*32 + nn*16 + li;
            #pragma unroll
            for (int r = 0; r < 4; ++r) {
                float v = acc[m][nn][r] + bias[oo + r];
                v = v > 0.f ? v : 0.1f*v;
                y1[((size_t)b*192 + oo + r)*PIX + px] = f2bf(v);
            }
        }
    }
}

// ---- fused depthwise-3x3 + dynamic conv + gate-sum; column windows ------
__global__ __launch_bounds__(256) void k_dwdyn3(
    const unsigned short* __restrict__ Y1,
    const unsigned short* __restrict__ X,
    const float* __restrict__ ws2,          // [192][9][9] = [c][j][tap]
    const float* __restrict__ bs2,          // [192*9]
    unsigned short* __restrict__ OP,
    float* __restrict__ gsum)               // [BSZ][192]
{
    const int c = blockIdx.x, b = blockIdx.y;
    __shared__ unsigned short ysm[4096];
    __shared__ unsigned short xsm[4096];
    __shared__ float red[4];
    const int tid = threadIdx.x;
    const size_t cb = ((size_t)b*192 + c) * PIX;
    #pragma unroll
    for (int j = 0; j < 2; ++j) {
        int i = tid + 256*j;
        *(uint4*)(ysm + i*8) = *(const uint4*)(Y1 + cb + i*8);
        *(uint4*)(xsm + i*8) = *(const uint4*)(X  + cb + i*8);
    }
    // weights -> registers (block-uniform addresses: scalar/broadcast loads)
    float wreg[81], breg[9];
    #pragma unroll
    for (int t = 0; t < 81; ++t) wreg[t] = ws2[c*81 + t];
    #pragma unroll
    for (int t = 0; t < 9; ++t) breg[t] = bs2[c*9 + t];
    __syncthreads();

    const int w = tid & 63, rg = tid >> 6, h0 = rg * 16;
    const bool wl = (w > 0), wr = (w < 63);

    float ya[3], yb[3], yc[3], xa[3], xb[3], xc[3];
    // prologue rows h0-1, h0
    {
        int h = h0 - 1;
        if (h >= 0) {
            int base = h*64 + w;
            ya[0] = wl ? bf2f(ysm[base-1]) : 0.f;  ya[1] = bf2f(ysm[base]);
            ya[2] = wr ? bf2f(ysm[base+1]) : 0.f;
            xa[0] = wl ? bf2f(xsm[base-1]) : 0.f;  xa[1] = bf2f(xsm[base]);
            xa[2] = wr ? bf2f(xsm[base+1]) : 0.f;
        } else { ya[0]=ya[1]=ya[2]=0.f; xa[0]=xa[1]=xa[2]=0.f; }
        int base = h0*64 + w;
        yb[0] = wl ? bf2f(ysm[base-1]) : 0.f;  yb[1] = bf2f(ysm[base]);
        yb[2] = wr ? bf2f(ysm[base+1]) : 0.f;
        xb[0] = wl ? bf2f(xsm[base-1]) : 0.f;  xb[1] = bf2f(xsm[base]);
        xb[2] = wr ? bf2f(xsm[base+1]) : 0.f;
    }

    float gacc = 0.f;
    #pragma unroll 4
    for (int j = 0; j < 16; ++j) {
        int h = h0 + j;
        // load row h+1 into (yc,xc)
        if (h + 1 < 64) {
            int base = (h+1)*64 + w;
            yc[0] = wl ? bf2f(ysm[base-1]) : 0.f;  yc[1] = bf2f(ysm[base]);
            yc[2] = wr ? bf2f(ysm[base+1]) : 0.f;
            xc[0] = wl ? bf2f(xsm[base-1]) : 0.f;  xc[1] = bf2f(xsm[base]);
            xc[2] = wr ? bf2f(xsm[base+1]) : 0.f;
        } else { yc[0]=yc[1]=yc[2]=0.f; xc[0]=xc[1]=xc[2]=0.f; }

        float ksp[9];
        #pragma unroll
        for (int t = 0; t < 9; ++t) ksp[t] = breg[t];
        #pragma unroll
        for (int tj = 0; tj < 3; ++tj) {
            #pragma unroll
            for (int t = 0; t < 9; ++t) ksp[t] += ya[tj] * wreg[t*9 + tj];
            #pragma unroll
            for (int t = 0; t < 9; ++t) ksp[t] += yb[tj] * wreg[t*9 + 3 + tj];
            #pragma unroll
            for (int t = 0; t < 9; ++t) ksp[t] += yc[tj] * wreg[t*9 + 6 + tj];
        }
        float out = xa[0]*ksp[0] + xa[1]*ksp[1] + xa[2]*ksp[2]
                  + xb[0]*ksp[3] + xb[1]*ksp[4] + xb[2]*ksp[5]
                  + xc[0]*ksp[6] + xc[1]*ksp[7] + xc[2]*ksp[8];
        OP[cb + h*64 + w] = f2bf(out);
        gacc += out;
        #pragma unroll
        for (int t = 0; t < 3; ++t) {
            ya[t] = yb[t]; yb[t] = yc[t];
            xa[t] = xb[t]; xb[t] = xc[t];
        }
    }
    #pragma unroll
    for (int off = 32; off > 0; off >>= 1) gacc += __shfl_down(gacc, off);
    if ((tid & 63) == 0) red[tid >> 6] = gacc;
    __syncthreads();
    if (tid == 0) gsum[b*192 + c] = red[0] + red[1] + red[2] + red[3];
}

// ---- SE gate ------------------------------------------------------------
__global__ void k_gate(const float* __restrict__ gsum,
                       const float* __restrict__ wc0, const float* __restrict__ bc0,
                       const float* __restrict__ wc1, const float* __restrict__ bc1,
                       float* __restrict__ gvec)
{
    const int b = blockIdx.x, t = threadIdx.x;
    __shared__ float mean[192], s1[192];
    mean[t] = gsum[b*192 + t] * (1.f/4096.f);
    __syncthreads();
    float a = bc0[t];
    const float* w = wc0 + t*192;
    for (int i = 0; i < 192; ++i) a += w[i] * mean[i];
    s1[t] = a > 0.f ? a : 0.1f * a;
    __syncthreads();
    float a2 = bc1[t];
    const float* w2 = wc1 + t*192;
    for (int i = 0; i < 192; ++i) a2 += w2[i] * s1[i];
    gvec[b*192 + t] = 1.f / (1.f + __expf(-a2));
}

// ---- final: out = Wo.(g*op) + bo + input --------------------------------
__global__ __launch_bounds__(256) void k_gemmo(
    const unsigned short* __restrict__ wof,
    const unsigned short* __restrict__ op,
    const float* __restrict__ bo,
    const float* __restrict__ gvec,
    const float* __restrict__ resid,
    float* __restrict__ out)
{
    const int b = blockIdx.y, n0 = blockIdx.x * 64;
    __shared__ unsigned short Bsm[192*66];
    const int tid = threadIdx.x, lane = tid & 63, wv = tid >> 6;
    const int li = lane & 15, kq = lane >> 4;

    {
        const unsigned short* src = op + (size_t)b*192*PIX + n0;
        #pragma unroll
        for (int j = 0; j < 6; ++j) {
            int q = tid + 256*j, k = q >> 3, g = (q & 7) * 8;
            uint4 v = *(const uint4*)(src + (size_t)k*PIX + g);
            float gs = gvec[b*192 + k];
            unsigned short* pv = (unsigned short*)&v;
            #pragma unroll
            for (int e = 0; e < 8; ++e) pv[e] = f2bf(bf2f(pv[e]) * gs);
            unsigned* d = (unsigned*)(Bsm + k*66 + g);
            const unsigned* s = (const unsigned*)&v;
            d[0]=s[0]; d[1]=s[1]; d[2]=s[2]; d[3]=s[3];
        }
    }
    __syncthreads();

    f32x4 acc[3][4];
    #pragma unroll
    for (int m = 0; m < 3; ++m)
        #pragma unroll
        for (int n = 0; n < 4; ++n) acc[m][n] = {0.f,0.f,0.f,0.f};
    for (int kc = 0; kc < 6; ++kc) {
        short8 a[3];
        #pragma unroll
        for (int m = 0; m < 3; ++m)
            a[m] = *(const short8*)(wof + ((kc*12 + wv*3 + m)*64 + lane)*8);
        #pragma unroll
        for (int n = 0; n < 4; ++n) {
            short8 fb = ldsBs(Bsm, 66, kc*32 + kq*8, n*16 + li);
            #pragma unroll
            for (int m = 0; m < 3; ++m)
                acc[m][n] = __builtin_amdgcn_mfma_f32_16x16x32_bf16(a[m], fb, acc[m][n], 0,0,0);
        }
    }
    #pragma unroll
    for (int m = 0; m < 3; ++m) {
        int o0 = (wv*3 + m)*16 + kq*4;
        #pragma unroll
        for (int n = 0; n < 4; ++n) {
            int px = n*16 + li;
            #pragma unroll
            for (int r = 0; r < 4; ++r) {
                size_t idx = ((size_t)b*192 + o0 + r)*PIX + n0 + px;
                out[idx] = acc[m][n][r] + bo[o0 + r] + resid[idx];
            }
        }
    }
}

extern "C" void kernel_launch(void* const* d_in, const int* in_sizes, int n_in,
                              void* d_out, int out_size, void* d_ws, size_t ws_size,
                              hipStream_t stream)
{
    const float* input = (const float*)d_in[0];
    const float* lc    = (const float*)d_in[1];
    const int*   mask  = (const int*)d_in[2];
    const float* w0  = (const float*)d_in[3];
    const float* b0  = (const float*)d_in[4];
    const float* w1  = (const float*)d_in[5];
    const float* b1  = (const float*)d_in[6];
    const float* ws0 = (const float*)d_in[7];
    const float* bs0 = (const float*)d_in[8];
    const float* ws1 = (const float*)d_in[9];
    const float* bs1 = (const float*)d_in[10];
    const float* ws2 = (const float*)d_in[11];
    const float* bs2 = (const float*)d_in[12];
    const float* wc0 = (const float*)d_in[13];
    const float* bc0 = (const float*)d_in[14];
    const float* wc1 = (const float*)d_in[15];
    const float* bc1 = (const float*)d_in[16];
    const float* wo  = (const float*)d_in[17];
    const float* bo  = (const float*)d_in[18];

    char* ws = (char*)d_ws;
    size_t off = 0;
    auto alloc = [&](size_t bytes) {
        void* p = ws + off; off = (off + bytes + 255) & ~(size_t)255; return p;
    };
    const size_t act_b = (size_t)BSZ * CH * PIX * 2;
    unsigned short* x_bf  = (unsigned short*)alloc(act_b);
    unsigned short* y0t   = (unsigned short*)alloc(act_b);   // [b][px][c]
    unsigned short* y1_bf = (unsigned short*)alloc(act_b);
    unsigned short* op_bf = (unsigned short*)alloc(act_b);
    unsigned short* w0f   = (unsigned short*)alloc(36864*2);
    unsigned short* w1f   = (unsigned short*)alloc(36864*2);
    unsigned short* ws0xf = (unsigned short*)alloc(36864*2);
    unsigned short* wof   = (unsigned short*)alloc(36864*2);
    unsigned short* wc3f  = (unsigned short*)alloc(331776*2);
    float* tc   = (float*)alloc(8*16*192*4);
    float* gsum = (float*)alloc(1536*4);
    float* gvec = (float*)alloc(1536*4);

    // 147456 (4 1x1 weights) + 331776 (conv wts) + 24576 (tcent) = 503808 = 1968*256
    k_prep_w<<<1968, 256, 0, stream>>>(w0, w1, ws0, wo, ws1, lc,
                                       w0f, w1f, ws0xf, wof, wc3f, tc);

    dim3 gg(64, 8);
    k_fused3<<<gg, 256, 0, stream>>>(input, w0f, w1f, ws0xf, b0, b1, bs0, tc, mask, x_bf, y0t);
    k_conv3t<<<gg, 512, 0, stream>>>(wc3f, y0t, bs1, y1_bf);
    k_dwdyn3<<<dim3(192, 8), 256, 0, stream>>>(y1_bf, x_bf, ws2, bs2, op_bf, gsum);
    k_gate<<<8, 192, 0, stream>>>(gsum, wc0, bc0, wc1, bc1, gvec);
    k_gemmo<<<gg, 256, 0, stream>>>(wof, op_bf, bo, gvec, input, (float*)d_out);
}

// Round 7
// 218.788 us; speedup vs baseline: 1.8784x; 1.0476x over previous
//
#include <hip/hip_runtime.h>
#include <hip/hip_bf16.h>

#define CH   192
#define PIX  4096   // 64*64 per image
#define BSZ  8

using f32x4  = __attribute__((ext_vector_type(4))) float;
using short8 = __attribute__((ext_vector_type(8))) short;

__device__ __forceinline__ float bf2f(unsigned short u) {
    union { unsigned u32; float f; } x; x.u32 = ((unsigned)u) << 16; return x.f;
}
__device__ __forceinline__ unsigned short f2bf(float f) {
    union { float f; unsigned u; } x; x.f = f;
    unsigned u = x.u;
    unsigned r = (u + 0x7FFFu + ((u >> 16) & 1u)) >> 16;  // RNE
    return (unsigned short)r;
}

// ---- prep: weights -> bf16 fragment-ordered; + tc; + gate-w transpose ---
__global__ void k_prep_w(const float* __restrict__ w0, const float* __restrict__ w1,
                         const float* __restrict__ ws0, const float* __restrict__ wo,
                         const float* __restrict__ ws1, const float* __restrict__ lc,
                         const float* __restrict__ wc0, const float* __restrict__ wc1,
                         unsigned short* __restrict__ w0f, unsigned short* __restrict__ w1f,
                         unsigned short* __restrict__ ws0xf, unsigned short* __restrict__ wof,
                         unsigned short* __restrict__ wc3f, float* __restrict__ tc,
                         float* __restrict__ wc0t, float* __restrict__ wc1t) {
    int i = blockIdx.x * 256 + threadIdx.x;
    if (i < 4*36864) {
        int which = i / 36864, j = i % 36864;
        int kc = j / 6144, r = j % 6144, mf = r / 512, r2 = r % 512;
        int l = r2 >> 3, e = r2 & 7;
        int o = mf*16 + (l & 15), k = kc*32 + ((l >> 4) << 3) + e;
        float v;
        unsigned short* dst;
        if (which == 0)      { v = w0[o*192 + k];  dst = w0f;   }
        else if (which == 1) { v = w1[o*192 + k];  dst = w1f;   }
        else if (which == 2) { v = ws0[o*384 + k]; dst = ws0xf; }
        else                 { v = wo[o*192 + k];  dst = wof;   }
        dst[j] = f2bf(v);
        return;
    }
    i -= 4*36864;
    if (i < 331776) {
        int tk = i / 6144, tap = tk / 6, kc = tk % 6;
        int r = i % 6144, mf = r / 512, r2 = r % 512;
        int l = r2 >> 3, e = r2 & 7;
        int o = mf*16 + (l & 15), c = kc*32 + ((l >> 4) << 3) + e;
        wc3f[i] = f2bf(ws1[(o*192 + c)*9 + tap]);
        return;
    }
    i -= 331776;
    if (i < 24576) {
        int bm = i / 192, o = i % 192;
        const float* wr = ws0 + o*384 + 192;
        const float* cb = lc + bm*192;
        float a = 0.f;
        for (int c2 = 0; c2 < 192; ++c2) a += wr[c2] * cb[c2];
        tc[i] = a;
        return;
    }
    i -= 24576;
    if (i < 36864) { int o = i / 192, c = i % 192; wc0t[c*192 + o] = wc0[o*192 + c]; return; }
    i -= 36864;
    if (i < 36864) { int o = i / 192, c = i % 192; wc1t[c*192 + o] = wc1[o*192 + c]; }
}

// ---- fused triple 1x1 GEMM: input(fp32) -> h -> x -> y0T ----------------
// B tiles px-major [64 px][200]: fragment reads are single ds_read_b128.
__global__ __launch_bounds__(256) void k_fused3(
    const float* __restrict__ input,
    const unsigned short* __restrict__ w0f,
    const unsigned short* __restrict__ w1f,
    const unsigned short* __restrict__ ws0xf,
    const float* __restrict__ b0, const float* __restrict__ b1,
    const float* __restrict__ bs0,
    const float* __restrict__ tc, const int* __restrict__ mask,
    unsigned short* __restrict__ xg, unsigned short* __restrict__ y0t)
{
    const int b = blockIdx.y, n0 = blockIdx.x * 64;
    __shared__ unsigned short Bsm[64*200];
    __shared__ unsigned short Csm[64*200];
    const int tid = threadIdx.x, lane = tid & 63, wv = tid >> 6;
    const int li = lane & 15, kq = lane >> 4;

    // stage input px-major, fp32 -> bf16
    {
        const float* src = input + (size_t)b*192*PIX + n0;
        #pragma unroll
        for (int j = 0; j < 6; ++j) {
            int q = tid + 256*j, k = q >> 3, g = (q & 7)*8;
            float4 v0 = *(const float4*)(src + (size_t)k*PIX + g);
            float4 v1 = *(const float4*)(src + (size_t)k*PIX + g + 4);
            Bsm[(g+0)*200 + k] = f2bf(v0.x);
            Bsm[(g+1)*200 + k] = f2bf(v0.y);
            Bsm[(g+2)*200 + k] = f2bf(v0.z);
            Bsm[(g+3)*200 + k] = f2bf(v0.w);
            Bsm[(g+4)*200 + k] = f2bf(v1.x);
            Bsm[(g+5)*200 + k] = f2bf(v1.y);
            Bsm[(g+6)*200 + k] = f2bf(v1.z);
            Bsm[(g+7)*200 + k] = f2bf(v1.w);
        }
    }
    __syncthreads();

    f32x4 acc[3][4];

    // ---- GEMM A: h = lrelu(W0.in + b0) -> Csm px-major
    #pragma unroll
    for (int m = 0; m < 3; ++m)
        #pragma unroll
        for (int n = 0; n < 4; ++n) acc[m][n] = {0.f,0.f,0.f,0.f};
    for (int kc = 0; kc < 6; ++kc) {
        short8 a[3];
        #pragma unroll
        for (int m = 0; m < 3; ++m)
            a[m] = *(const short8*)(w0f + ((kc*12 + wv*3 + m)*64 + lane)*8);
        #pragma unroll
        for (int n = 0; n < 4; ++n) {
            short8 fb = *(const short8*)(Bsm + (n*16 + li)*200 + kc*32 + kq*8);
            #pragma unroll
            for (int m = 0; m < 3; ++m)
                acc[m][n] = __builtin_amdgcn_mfma_f32_16x16x32_bf16(a[m], fb, acc[m][n], 0,0,0);
        }
    }
    #pragma unroll
    for (int m = 0; m < 3; ++m) {
        int o0 = (wv*3 + m)*16 + kq*4;
        #pragma unroll
        for (int n = 0; n < 4; ++n) {
            int px = n*16 + li;
            ushort4 w;
            unsigned short* wp = (unsigned short*)&w;
            #pragma unroll
            for (int r = 0; r < 4; ++r) {
                float v = acc[m][n][r] + b0[o0 + r];
                v = v > 0.f ? v : 0.1f*v;
                wp[r] = f2bf(v);
            }
            *(ushort4*)(Csm + px*200 + o0) = w;
        }
    }
    __syncthreads();

    // ---- GEMM B: x = W1.h + b1 -> Bsm px-major + global xg
    #pragma unroll
    for (int m = 0; m < 3; ++m)
        #pragma unroll
        for (int n = 0; n < 4; ++n) acc[m][n] = {0.f,0.f,0.f,0.f};
    for (int kc = 0; kc < 6; ++kc) {
        short8 a[3];
        #pragma unroll
        for (int m = 0; m < 3; ++m)
            a[m] = *(const short8*)(w1f + ((kc*12 + wv*3 + m)*64 + lane)*8);
        #pragma unroll
        for (int n = 0; n < 4; ++n) {
            short8 fb = *(const short8*)(Csm + (n*16 + li)*200 + kc*32 + kq*8);
            #pragma unroll
            for (int m = 0; m < 3; ++m)
                acc[m][n] = __builtin_amdgcn_mfma_f32_16x16x32_bf16(a[m], fb, acc[m][n], 0,0,0);
        }
    }
    #pragma unroll
    for (int m = 0; m < 3; ++m) {
        int o0 = (wv*3 + m)*16 + kq*4;
        #pragma unroll
        for (int n = 0; n < 4; ++n) {
            int px = n*16 + li;
            ushort4 w;
            unsigned short* wp = (unsigned short*)&w;
            #pragma unroll
            for (int r = 0; r < 4; ++r) {
                float v = acc[m][n][r] + b1[o0 + r];
                unsigned short h = f2bf(v);
                wp[r] = h;
                xg[((size_t)b*192 + o0 + r)*PIX + n0 + px] = h;
            }
            *(ushort4*)(Bsm + px*200 + o0) = w;
        }
    }
    __syncthreads();

    // ---- GEMM C: y0 = lrelu(Ws0x.x + bs0 + tc[mask]) -> Csm px-major -> y0T
    #pragma unroll
    for (int m = 0; m < 3; ++m)
        #pragma unroll
        for (int n = 0; n < 4; ++n) acc[m][n] = {0.f,0.f,0.f,0.f};
    for (int kc = 0; kc < 6; ++kc) {
        short8 a[3];
        #pragma unroll
        for (int m = 0; m < 3; ++m)
            a[m] = *(const short8*)(ws0xf + ((kc*12 + wv*3 + m)*64 + lane)*8);
        #pragma unroll
        for (int n = 0; n < 4; ++n) {
            short8 fb = *(const short8*)(Bsm + (n*16 + li)*200 + kc*32 + kq*8);
            #pragma unroll
            for (int m = 0; m < 3; ++m)
                acc[m][n] = __builtin_amdgcn_mfma_f32_16x16x32_bf16(a[m], fb, acc[m][n], 0,0,0);
        }
    }
    int mi_[4];
    #pragma unroll
    for (int n = 0; n < 4; ++n) mi_[n] = mask[b*PIX + n0 + n*16 + li];
    #pragma unroll
    for (int m = 0; m < 3; ++m) {
        int o0 = (wv*3 + m)*16 + kq*4;
        #pragma unroll
        for (int n = 0; n < 4; ++n) {
            int px = n*16 + li;
            const float* tcb = tc + (b*16 + mi_[n])*192;
            ushort4 w;
            unsigned short* wp = (unsigned short*)&w;
            #pragma unroll
            for (int r = 0; r < 4; ++r) {
                float v = acc[m][n][r] + bs0[o0 + r] + tcb[o0 + r];
                v = v > 0.f ? v : 0.1f*v;
                wp[r] = f2bf(v);
            }
            *(ushort4*)(Csm + px*200 + o0) = w;
        }
    }
    __syncthreads();
    // coalesced y0T store: [b][n0+px][c]
    #pragma unroll
    for (int j = 0; j < 6; ++j) {
        int u = tid + 256*j;           // 1536 units = 64 px * 24 chunks
        int px = u / 24, chunk = u % 24;
        uint4 v = *(const uint4*)(Csm + px*200 + chunk*8);
        *(uint4*)(y0t + ((size_t)(b*4096 + n0 + px))*192 + chunk*8) = v;
    }
}

// ---- 3x3 conv: 8 waves; double-buffered LDS, issue-early/commit-late ----
__global__ __launch_bounds__(512) void k_conv3t(
    const unsigned short* __restrict__ wc3f,
    const unsigned short* __restrict__ y0t,   // [b][4096 px][192 c]
    const float* __restrict__ bias,
    unsigned short* __restrict__ y1)          // [b][c][4096 px]
{
    const int b = blockIdx.y, h = blockIdx.x;
    __shared__ unsigned short Bs[2][3*66*40]; // [buf][dr][pxl][40 shorts], 80B rows
    const int tid = threadIdx.x, lane = tid & 63, wv = tid >> 6;
    const int li = lane & 15, kq = lane >> 4;
    const int mw = wv >> 1, nh = wv & 1;      // M-quarter, N-half

    const int u1 = tid + 512;
    const int r0 = tid >> 2,  c0 = tid & 3;
    const int dr0 = r0/66, px0g = r0%66 - 1, hh0 = h + dr0 - 1;
    const bool ok0 = ((unsigned)hh0 < 64u) & ((unsigned)px0g < 64u);
    const size_t s0 = ok0 ? ((size_t)(b*4096 + hh0*64 + px0g))*192 + c0*8 : 0;
    const int o0f = r0*80 + c0*16;
    const int r1 = u1 >> 2,  c1 = u1 & 3;
    const int dr1 = r1/66, px1g = r1%66 - 1, hh1 = h + dr1 - 1;
    const bool act1 = (u1 < 792);
    const bool ok1 = act1 & ((unsigned)hh1 < 64u) & ((unsigned)px1g < 64u);
    const size_t s1 = ok1 ? ((size_t)(b*4096 + hh1*64 + px1g))*192 + c1*8 : 0;
    const int o1f = r1*80 + c1*16;
    const uint4 zz = {0u,0u,0u,0u};

    uint4 v0, v1;
    v0 = ok0 ? *(const uint4*)(y0t + s0) : zz;
    v1 = ok1 ? *(const uint4*)(y0t + s1) : zz;
    *(uint4*)((char*)Bs[0] + o0f) = v0;
    if (act1) *(uint4*)((char*)Bs[0] + o1f) = v1;
    __syncthreads();

    f32x4 acc[3][2];
    #pragma unroll
    for (int m = 0; m < 3; ++m)
        #pragma unroll
        for (int nn = 0; nn < 2; ++nn) acc[m][nn] = {0.f,0.f,0.f,0.f};

    for (int kc = 0; kc < 6; ++kc) {
        const int cur = kc & 1;
        if (kc < 5) {
            v0 = ok0 ? *(const uint4*)(y0t + s0 + (kc+1)*32) : zz;
            v1 = ok1 ? *(const uint4*)(y0t + s1 + (kc+1)*32) : zz;
        }
        const unsigned short* Bc = Bs[cur];
        #pragma unroll
        for (int tap = 0; tap < 9; ++tap) {
            const int dr = tap / 3, dc1 = tap % 3;
            short8 a[3];
            #pragma unroll
            for (int m = 0; m < 3; ++m)
                a[m] = *(const short8*)(wc3f + (((tap*6 + kc)*12 + mw*3 + m)*64 + lane)*8);
            #pragma unroll
            for (int nn = 0; nn < 2; ++nn) {
                int pxi = nh*32 + nn*16 + li + dc1;
                short8 fb = *(const short8*)((const char*)Bc + (dr*66 + pxi)*80 + kq*16);
                #pragma unroll
                for (int m = 0; m < 3; ++m)
                    acc[m][nn] = __builtin_amdgcn_mfma_f32_16x16x32_bf16(a[m], fb, acc[m][nn], 0,0,0);
            }
        }
        if (kc < 5) {
            *(uint4*)((char*)Bs[cur^1] + o0f) = v0;
            if (act1) *(uint4*)((char*)Bs[cur^1] + o1f) = v1;
            __syncthreads();
        }
    }

    #pragma unroll
    for (int m = 0; m < 3; ++m) {
        int oo = (mw*3 + m)*16 + kq*4;
        #pragma unroll
        for (int nn = 0; nn < 2; ++nn) {
            int px = h*64 + nh*32 + nn*16 + li;
            #pragma unroll
            for (int r = 0; r < 4; ++r) {
                float v = acc[m][nn][r] + bias[oo + r];
                v = v > 0.f ? v : 0.1f*v;
                y1[((size_t)b*192 + oo + r)*PIX + px] = f2bf(v);
            }
        }
    }
}

// ---- fused depthwise-3x3 + dynamic conv + gate-sum; column windows ------
__global__ __launch_bounds__(256) void k_dwdyn3(
    const unsigned short* __restrict__ Y1,
    const unsigned short* __restrict__ X,
    const float* __restrict__ ws2,          // [192][9][9] = [c][j][tap]
    const float* __restrict__ bs2,          // [192*9]
    unsigned short* __restrict__ OP,
    float* __restrict__ gsum)               // [BSZ][192]
{
    const int c = blockIdx.x, b = blockIdx.y;
    __shared__ unsigned short ysm[4096];
    __shared__ unsigned short xsm[4096];
    __shared__ float red[4];
    const int tid = threadIdx.x;
    const size_t cb = ((size_t)b*192 + c) * PIX;
    #pragma unroll
    for (int j = 0; j < 2; ++j) {
        int i = tid + 256*j;
        *(uint4*)(ysm + i*8) = *(const uint4*)(Y1 + cb + i*8);
        *(uint4*)(xsm + i*8) = *(const uint4*)(X  + cb + i*8);
    }
    float wreg[81], breg[9];
    #pragma unroll
    for (int t = 0; t < 81; ++t) wreg[t] = ws2[c*81 + t];
    #pragma unroll
    for (int t = 0; t < 9; ++t) breg[t] = bs2[c*9 + t];
    __syncthreads();

    const int w = tid & 63, rg = tid >> 6, h0 = rg * 16;
    const bool wl = (w > 0), wr = (w < 63);

    float ya[3], yb[3], yc[3], xa[3], xb[3], xc[3];
    {
        int h = h0 - 1;
        if (h >= 0) {
            int base = h*64 + w;
            ya[0] = wl ? bf2f(ysm[base-1]) : 0.f;  ya[1] = bf2f(ysm[base]);
            ya[2] = wr ? bf2f(ysm[base+1]) : 0.f;
            xa[0] = wl ? bf2f(xsm[base-1]) : 0.f;  xa[1] = bf2f(xsm[base]);
            xa[2] = wr ? bf2f(xsm[base+1]) : 0.f;
        } else { ya[0]=ya[1]=ya[2]=0.f; xa[0]=xa[1]=xa[2]=0.f; }
        int base = h0*64 + w;
        yb[0] = wl ? bf2f(ysm[base-1]) : 0.f;  yb[1] = bf2f(ysm[base]);
        yb[2] = wr ? bf2f(ysm[base+1]) : 0.f;
        xb[0] = wl ? bf2f(xsm[base-1]) : 0.f;  xb[1] = bf2f(xsm[base]);
        xb[2] = wr ? bf2f(xsm[base+1]) : 0.f;
    }

    float gacc = 0.f;
    #pragma unroll 4
    for (int j = 0; j < 16; ++j) {
        int h = h0 + j;
        if (h + 1 < 64) {
            int base = (h+1)*64 + w;
            yc[0] = wl ? bf2f(ysm[base-1]) : 0.f;  yc[1] = bf2f(ysm[base]);
            yc[2] = wr ? bf2f(ysm[base+1]) : 0.f;
            xc[0] = wl ? bf2f(xsm[base-1]) : 0.f;  xc[1] = bf2f(xsm[base]);
            xc[2] = wr ? bf2f(xsm[base+1]) : 0.f;
        } else { yc[0]=yc[1]=yc[2]=0.f; xc[0]=xc[1]=xc[2]=0.f; }

        float ksp[9];
        #pragma unroll
        for (int t = 0; t < 9; ++t) ksp[t] = breg[t];
        #pragma unroll
        for (int tj = 0; tj < 3; ++tj) {
            #pragma unroll
            for (int t = 0; t < 9; ++t) ksp[t] += ya[tj] * wreg[t*9 + tj];
            #pragma unroll
            for (int t = 0; t < 9; ++t) ksp[t] += yb[tj] * wreg[t*9 + 3 + tj];
            #pragma unroll
            for (int t = 0; t < 9; ++t) ksp[t] += yc[tj] * wreg[t*9 + 6 + tj];
        }
        float out = xa[0]*ksp[0] + xa[1]*ksp[1] + xa[2]*ksp[2]
                  + xb[0]*ksp[3] + xb[1]*ksp[4] + xb[2]*ksp[5]
                  + xc[0]*ksp[6] + xc[1]*ksp[7] + xc[2]*ksp[8];
        OP[cb + h*64 + w] = f2bf(out);
        gacc += out;
        #pragma unroll
        for (int t = 0; t < 3; ++t) {
            ya[t] = yb[t]; yb[t] = yc[t];
            xa[t] = xb[t]; xb[t] = xc[t];
        }
    }
    #pragma unroll
    for (int off = 32; off > 0; off >>= 1) gacc += __shfl_down(gacc, off);
    if ((tid & 63) == 0) red[tid >> 6] = gacc;
    __syncthreads();
    if (tid == 0) gsum[b*192 + c] = red[0] + red[1] + red[2] + red[3];
}

// ---- final: gate MLP (per-block) + out = Wo.(g*op) + bo + input ---------
__global__ __launch_bounds__(256) void k_gemmo(
    const unsigned short* __restrict__ wof,
    const unsigned short* __restrict__ op,
    const float* __restrict__ bo,
    const float* __restrict__ gsum,
    const float* __restrict__ wc0t, const float* __restrict__ bc0,
    const float* __restrict__ wc1t, const float* __restrict__ bc1,
    const float* __restrict__ resid,
    float* __restrict__ out)
{
    const int b = blockIdx.y, n0 = blockIdx.x * 64;
    __shared__ unsigned short Bsm[64*200];
    __shared__ float mean[192], s1[192], gv[192];
    const int tid = threadIdx.x, lane = tid & 63, wv = tid >> 6;
    const int li = lane & 15, kq = lane >> 4;

    // gate MLP from gsum (redundant per block; coalesced via transposed wts)
    if (tid < 192) mean[tid] = gsum[b*192 + tid] * (1.f/4096.f);
    __syncthreads();
    if (tid < 192) {
        float a = bc0[tid];
        for (int i = 0; i < 192; ++i) a += wc0t[i*192 + tid] * mean[i];
        s1[tid] = a > 0.f ? a : 0.1f * a;
    }
    __syncthreads();
    if (tid < 192) {
        float a2 = bc1[tid];
        for (int i = 0; i < 192; ++i) a2 += wc1t[i*192 + tid] * s1[i];
        gv[tid] = 1.f / (1.f + __expf(-a2));
    }
    __syncthreads();

    // stage op scaled by gv[c], px-major
    {
        const unsigned short* src = op + (size_t)b*192*PIX + n0;
        #pragma unroll
        for (int j = 0; j < 6; ++j) {
            int q = tid + 256*j, c = q >> 3, g = (q & 7) * 8;
            uint4 v = *(const uint4*)(src + (size_t)c*PIX + g);
            float gs = gv[c];
            const unsigned short* pv = (const unsigned short*)&v;
            #pragma unroll
            for (int e = 0; e < 8; ++e)
                Bsm[(g+e)*200 + c] = f2bf(bf2f(pv[e]) * gs);
        }
    }
    __syncthreads();

    f32x4 acc[3][4];
    #pragma unroll
    for (int m = 0; m < 3; ++m)
        #pragma unroll
        for (int n = 0; n < 4; ++n) acc[m][n] = {0.f,0.f,0.f,0.f};
    for (int kc = 0; kc < 6; ++kc) {
        short8 a[3];
        #pragma unroll
        for (int m = 0; m < 3; ++m)
            a[m] = *(const short8*)(wof + ((kc*12 + wv*3 + m)*64 + lane)*8);
        #pragma unroll
        for (int n = 0; n < 4; ++n) {
            short8 fb = *(const short8*)(Bsm + (n*16 + li)*200 + kc*32 + kq*8);
            #pragma unroll
            for (int m = 0; m < 3; ++m)
                acc[m][n] = __builtin_amdgcn_mfma_f32_16x16x32_bf16(a[m], fb, acc[m][n], 0,0,0);
        }
    }
    #pragma unroll
    for (int m = 0; m < 3; ++m) {
        int o0 = (wv*3 + m)*16 + kq*4;
        #pragma unroll
        for (int n = 0; n < 4; ++n) {
            int px = n*16 + li;
            #pragma unroll
            for (int r = 0; r < 4; ++r) {
                size_t idx = ((size_t)b*192 + o0 + r)*PIX + n0 + px;
                out[idx] = acc[m][n][r] + bo[o0 + r] + resid[idx];
            }
        }
    }
}

extern "C" void kernel_launch(void* const* d_in, const int* in_sizes, int n_in,
                              void* d_out, int out_size, void* d_ws, size_t ws_size,
                              hipStream_t stream)
{
    const float* input = (const float*)d_in[0];
    const float* lc    = (const float*)d_in[1];
    const int*   mask  = (const int*)d_in[2];
    const float* w0  = (const float*)d_in[3];
    const float* b0  = (const float*)d_in[4];
    const float* w1  = (const float*)d_in[5];
    const float* b1  = (const float*)d_in[6];
    const float* ws0 = (const float*)d_in[7];
    const float* bs0 = (const float*)d_in[8];
    const float* ws1 = (const float*)d_in[9];
    const float* bs1 = (const float*)d_in[10];
    const float* ws2 = (const float*)d_in[11];
    const float* bs2 = (const float*)d_in[12];
    const float* wc0 = (const float*)d_in[13];
    const float* bc0 = (const float*)d_in[14];
    const float* wc1 = (const float*)d_in[15];
    const float* bc1 = (const float*)d_in[16];
    const float* wo  = (const float*)d_in[17];
    const float* bo  = (const float*)d_in[18];

    char* ws = (char*)d_ws;
    size_t off = 0;
    auto alloc = [&](size_t bytes) {
        void* p = ws + off; off = (off + bytes + 255) & ~(size_t)255; return p;
    };
    const size_t act_b = (size_t)BSZ * CH * PIX * 2;
    unsigned short* x_bf  = (unsigned short*)alloc(act_b);
    unsigned short* y0t   = (unsigned short*)alloc(act_b);   // [b][px][c]
    unsigned short* y1_bf = (unsigned short*)alloc(act_b);
    unsigned short* op_bf = (unsigned short*)alloc(act_b);
    unsigned short* w0f   = (unsigned short*)alloc(36864*2);
    unsigned short* w1f   = (unsigned short*)alloc(36864*2);
    unsigned short* ws0xf = (unsigned short*)alloc(36864*2);
    unsigned short* wof   = (unsigned short*)alloc(36864*2);
    unsigned short* wc3f  = (unsigned short*)alloc(331776*2);
    float* tc    = (float*)alloc(8*16*192*4);
    float* gsum  = (float*)alloc(1536*4);
    float* wc0t  = (float*)alloc(36864*4);
    float* wc1t  = (float*)alloc(36864*4);

    // 147456 + 331776 + 24576 + 36864 + 36864 = 577536 = 2256*256
    k_prep_w<<<2256, 256, 0, stream>>>(w0, w1, ws0, wo, ws1, lc, wc0, wc1,
                                       w0f, w1f, ws0xf, wof, wc3f, tc, wc0t, wc1t);

    dim3 gg(64, 8);
    k_fused3<<<gg, 256, 0, stream>>>(input, w0f, w1f, ws0xf, b0, b1, bs0, tc, mask, x_bf, y0t);
    k_conv3t<<<gg, 512, 0, stream>>>(wc3f, y0t, bs1, y1_bf);
    k_dwdyn3<<<dim3(192, 8), 256, 0, stream>>>(y1_bf, x_bf, ws2, bs2, op_bf, gsum);
    k_gemmo<<<gg, 256, 0, stream>>>(wof, op_bf, bo, gsum, wc0t, bc0, wc1t, bc1,
                                    input, (float*)d_out);
}